// Round 1
// baseline (449.459 us; speedup 1.0000x reference)
//
#include <hip/hip_runtime.h>

typedef _Float16 f16;
typedef f16  f16x8 __attribute__((ext_vector_type(8)));
typedef f16  f16x4 __attribute__((ext_vector_type(4)));
typedef float f32x4 __attribute__((ext_vector_type(4)));

__device__ __forceinline__ void gld_lds16(const f16* g, void* l) {
  __builtin_amdgcn_global_load_lds((const __attribute__((address_space(1))) void*)g,
                                   (__attribute__((address_space(3))) void*)l,
                                   16, 0, 0);
}

__device__ __forceinline__ unsigned encf(float x) {
  unsigned u = __float_as_uint(x);
  return (u & 0x80000000u) ? ~u : (u | 0x80000000u);
}
__device__ __forceinline__ float decf(unsigned e) {
  unsigned u = (e & 0x80000000u) ? (e ^ 0x80000000u) : ~e;
  return __uint_as_float(u);
}

enum { EPI_SCORES = 0, EPI_BIAS = 1, EPI_RELU = 2, EPI_OUT = 3 };

// C[M,N] = A[M,K] @ B[N,K]^T, 128x128 tile, BK=32, 4 waves (2x2), 16x16x32 f16 MFMA.
template<int EPI>
__global__ __launch_bounds__(256)
void gemm_bt(const f16* __restrict__ A, const f16* __restrict__ B, void* __restrict__ C,
             int lda, int ldb, int ldc, int K,
             long long sA, long long sB, long long sC,
             const float* __restrict__ bias, float scale,
             unsigned* __restrict__ mm,
             const float* __restrict__ wfb, const float* __restrict__ dvv)
{
  __shared__ __align__(16) f16 As[128][32];
  __shared__ __align__(16) f16 Bs[128][32];
  const int tid  = threadIdx.x;
  const int lane = tid & 63;
  const int w    = tid >> 6;
  const int wm   = w >> 1, wn = w & 1;
  const int z    = blockIdx.z;
  const int m0   = blockIdx.y * 128, n0 = blockIdx.x * 128;
  const f16* Ab = A + (size_t)z * sA + (size_t)m0 * lda;
  const f16* Bb = B + (size_t)z * sB + (size_t)n0 * ldb;

  f32x4 acc[4][4] = {};

  for (int k0 = 0; k0 < K; k0 += 32) {
#pragma unroll
    for (int i = 0; i < 2; ++i) {
      const int ci = i * 256 + tid;       // chunk index 0..511, 16B each
      const int r  = ci >> 2;             // tile row
      const int sg = ci & 3;              // 16B segment within 64B row
      gld_lds16(Ab + (size_t)r * lda + k0 + sg * 8,
                (char*)As + (size_t)(i * 256 + w * 64) * 16);
      gld_lds16(Bb + (size_t)r * ldb + k0 + sg * 8,
                (char*)Bs + (size_t)(i * 256 + w * 64) * 16);
    }
    __syncthreads();
    f16x8 af[4], bfr[4];
#pragma unroll
    for (int m = 0; m < 4; ++m)
      af[m] = *(const f16x8*)&As[wm * 64 + m * 16 + (lane & 15)][(lane >> 4) * 8];
#pragma unroll
    for (int n = 0; n < 4; ++n)
      bfr[n] = *(const f16x8*)&Bs[wn * 64 + n * 16 + (lane & 15)][(lane >> 4) * 8];
#pragma unroll
    for (int m = 0; m < 4; ++m)
#pragma unroll
      for (int n = 0; n < 4; ++n)
        acc[m][n] = __builtin_amdgcn_mfma_f32_16x16x32_f16(af[m], bfr[n], acc[m][n], 0, 0, 0);
    __syncthreads();
  }

  const int col_l = lane & 15;
  const int row_l = (lane >> 4) << 2;

  if constexpr (EPI == EPI_SCORES) {
    float* Cf = (float*)C + (size_t)z * sC + (size_t)m0 * ldc + n0;
    float lmax = -3.402823466e38f, lmin = 3.402823466e38f;
#pragma unroll
    for (int m = 0; m < 4; ++m)
#pragma unroll
      for (int n = 0; n < 4; ++n)
#pragma unroll
        for (int r = 0; r < 4; ++r) {
          float val = acc[m][n][r] * scale;
          lmax = fmaxf(lmax, val); lmin = fminf(lmin, val);
          Cf[(size_t)(wm * 64 + m * 16 + row_l + r) * ldc + (wn * 64 + n * 16 + col_l)] = val;
        }
#pragma unroll
    for (int off = 32; off >= 1; off >>= 1) {
      lmax = fmaxf(lmax, __shfl_xor(lmax, off));
      lmin = fminf(lmin, __shfl_xor(lmin, off));
    }
    if (lane == 0) {
      atomicMax(&mm[0], encf(lmax));
      atomicMin(&mm[1], encf(lmin));
    }
  } else {
    f16* Ch = (f16*)C + (size_t)z * sC + (size_t)m0 * ldc + n0;
#pragma unroll
    for (int m = 0; m < 4; ++m)
#pragma unroll
      for (int n = 0; n < 4; ++n)
#pragma unroll
        for (int r = 0; r < 4; ++r) {
          const int rr = wm * 64 + m * 16 + row_l + r;
          const int cc = wn * 64 + n * 16 + col_l;
          float val = acc[m][n][r];
          if constexpr (EPI == EPI_BIAS || EPI == EPI_RELU) val += bias[n0 + cc];
          if constexpr (EPI == EPI_RELU) val = fmaxf(val, 0.0f);
          if constexpr (EPI == EPI_OUT)
            val += wfb[z * 1024 + m0 + rr] * dvv[z * 512 + n0 + cc];
          Ch[(size_t)rr * ldc + cc] = (f16)val;
        }
  }
}

__global__ void f32_to_f16_k(const float* __restrict__ in, f16* __restrict__ outp, int n4)
{
  int i = blockIdx.x * 256 + threadIdx.x;
  if (i >= n4) return;
  float4 v = *(const float4*)(in + (size_t)i * 4);
  f16x4 o = { (f16)v.x, (f16)v.y, (f16)v.z, (f16)v.w };
  *(f16x4*)(outp + (size_t)i * 4) = o;
}

// one block: count nonzero bytes of mask (dtype sniffing) + init min/max atomics
__global__ void init_count(const unsigned char* __restrict__ mask, unsigned* __restrict__ mm)
{
  __shared__ int red[256];
  int c = 0;
  for (int i = threadIdx.x; i < 16384; i += 256) c += (mask[i] != 0) ? 1 : 0;
  red[threadIdx.x] = c;
  __syncthreads();
  for (int s = 128; s > 0; s >>= 1) {
    if (threadIdx.x < s) red[threadIdx.x] += red[threadIdx.x + s];
    __syncthreads();
  }
  if (threadIdx.x == 0) {
    mm[0] = 0u;            // max encode accumulator
    mm[1] = 0xFFFFFFFFu;   // min encode accumulator
    mm[2] = (unsigned)red[0];
  }
}

__global__ void fb_kernel(const float* __restrict__ fallback, unsigned* __restrict__ mm,
                          float* __restrict__ fbws)
{
  float bmax = decf(mm[0]);
  float bmin = decf(mm[1]);
  fbws[0] = 0.99f * fallback[0] + 0.01f * 0.5f * (bmax + bmin);
  mm[3] = (mm[2] > 5000u) ? 1u : 0u;   // 1 = byte mask, 0 = int32 mask
}

__global__ __launch_bounds__(256)
void softmax_rows(const float* __restrict__ scores, const void* __restrict__ maskp,
                  const float* __restrict__ fbp, const unsigned* __restrict__ modep,
                  f16* __restrict__ Wt, float* __restrict__ wfb)
{
  __shared__ float red[8];
  const int row  = blockIdx.x;
  const int b    = row >> 10;
  const int tid  = threadIdx.x;
  const int lane = tid & 63, w = tid >> 6;
  const float fb = *fbp;
  const unsigned mode = *modep;
  const float* s = scores + (size_t)row * 1024;
  const int k0 = tid * 4;
  float4 v = *(const float4*)(s + k0);
  float x[4];
  if (mode) {
    const unsigned char* m8 = (const unsigned char*)maskp + b * 1024 + k0;
    x[0] = m8[0] ? -1e9f : v.x;  x[1] = m8[1] ? -1e9f : v.y;
    x[2] = m8[2] ? -1e9f : v.z;  x[3] = m8[3] ? -1e9f : v.w;
  } else {
    const int* mi = (const int*)maskp + b * 1024 + k0;
    x[0] = mi[0] ? -1e9f : v.x;  x[1] = mi[1] ? -1e9f : v.y;
    x[2] = mi[2] ? -1e9f : v.z;  x[3] = mi[3] ? -1e9f : v.w;
  }
  float mx = fmaxf(fmaxf(x[0], x[1]), fmaxf(x[2], x[3]));
#pragma unroll
  for (int off = 32; off >= 1; off >>= 1) mx = fmaxf(mx, __shfl_xor(mx, off));
  if (lane == 0) red[w] = mx;
  __syncthreads();
  mx = fmaxf(fmaxf(fmaxf(red[0], red[1]), fmaxf(red[2], red[3])), fb);
  float e0 = expf(x[0] - mx), e1 = expf(x[1] - mx), e2 = expf(x[2] - mx), e3 = expf(x[3] - mx);
  float sum = (e0 + e1) + (e2 + e3);
#pragma unroll
  for (int off = 32; off >= 1; off >>= 1) sum += __shfl_xor(sum, off);
  if (lane == 0) red[4 + w] = sum;
  __syncthreads();
  float efb = expf(fb - mx);
  float Z = ((red[4] + red[5]) + (red[6] + red[7])) + efb;
  float inv = 1.0f / Z;
  f16x4 o = { (f16)(e0 * inv), (f16)(e1 * inv), (f16)(e2 * inv), (f16)(e3 * inv) };
  *(f16x4*)&Wt[(size_t)row * 1024 + k0] = o;
  if (tid == 0) wfb[row] = efb * inv;
}

__global__ __launch_bounds__(256)
void transpose_k(const f16* __restrict__ vp, f16* __restrict__ vpt)
{
  __shared__ __align__(16) f16 t[64][72];
  const int b = blockIdx.z, dx = blockIdx.x, ky = blockIdx.y;
  const int tid = threadIdx.x;
  const f16* src = vp + ((size_t)b * 1024 + ky * 64) * 512 + dx * 64;
#pragma unroll
  for (int it = 0; it < 2; ++it) {
    int r  = (tid >> 3) + it * 32;
    int c8 = (tid & 7) * 8;
    f16x8 vv = *(const f16x8*)(src + (size_t)r * 512 + c8);
#pragma unroll
    for (int j = 0; j < 8; ++j) t[r][c8 + j] = vv[j];
  }
  __syncthreads();
  f16* dst = vpt + ((size_t)b * 512 + dx * 64) * 1024 + ky * 64;
#pragma unroll
  for (int it = 0; it < 2; ++it) {
    int c  = (tid >> 3) + it * 32;
    int r8 = (tid & 7) * 8;
    f16x8 o;
#pragma unroll
    for (int j = 0; j < 8; ++j) o[j] = t[r8 + j][c];
    *(f16x8*)(dst + (size_t)c * 1024 + r8) = o;
  }
}

__global__ void dv_kernel(const float* __restrict__ uq, const float* __restrict__ Wf,
                          const float* __restrict__ bfv, float* __restrict__ dv)
{
  int t = blockIdx.x * 256 + threadIdx.x;   // 0..8191
  int b = t >> 9, j = t & 511;
  const float4* x  = (const float4*)(uq + b * 512);
  const float4* wr = (const float4*)(Wf + (size_t)j * 512);
  float s = 0.f;
  for (int d = 0; d < 128; ++d) {
    float4 a = x[d], bw = wr[d];
    s += a.x * bw.x + a.y * bw.y + a.z * bw.z + a.w * bw.w;
  }
  dv[t] = s + bfv[j];
}

__global__ void fc_relu_k(const float* __restrict__ X, const float* __restrict__ Wm,
                          const float* __restrict__ bb, float* __restrict__ Y,
                          int In, int OutN)
{
  int t = blockIdx.x * 256 + threadIdx.x;
  int b = t / OutN, j = t - b * OutN;
  const float* x  = X + b * In;
  const float* wr = Wm + (size_t)j * In;
  float s = 0.f;
  for (int d = 0; d < In; ++d) s += x[d] * wr[d];
  Y[t] = fmaxf(s + bb[j], 0.f);
}

__global__ void fc3_k(const float* __restrict__ h2d, const float* __restrict__ W3,
                      const float* __restrict__ b3, float* __restrict__ outp)
{
  int b = threadIdx.x;
  if (b < 16) {
    const float* x = h2d + b * 256;
    float s = 0.f;
    for (int d = 0; d < 256; ++d) s += x[d] * W3[d];
    outp[b] = tanhf(s + b3[0]);
  }
}

__global__ __launch_bounds__(256)
void y_kernel(const f16* __restrict__ h2, const float* __restrict__ W3,
              const float* __restrict__ b3, float* __restrict__ outp)
{
  int row = blockIdx.x * 16 + (threadIdx.x >> 4);
  int l   = threadIdx.x & 15;
  const f16* h = h2 + (size_t)row * 256 + l * 16;
  float s = 0.f;
#pragma unroll
  for (int j = 0; j < 16; ++j) s += (float)h[j] * W3[l * 16 + j];
#pragma unroll
  for (int off = 1; off < 16; off <<= 1) s += __shfl_xor(s, off);
  if (l == 0) outp[row] = tanhf(s + b3[0]);
}

extern "C" void kernel_launch(void* const* d_in, const int* in_sizes, int n_in,
                              void* d_out, int out_size, void* d_ws, size_t ws_size,
                              hipStream_t stream) {
  const float* uq       = (const float*)d_in[0];
  const float* q        = (const float*)d_in[1];
  const float* kk       = (const float*)d_in[2];
  const float* v        = (const float*)d_in[3];
  const void*  mask     = d_in[4];
  const float* fallback = (const float*)d_in[5];
  const float* Wv = (const float*)d_in[6];
  const float* bv = (const float*)d_in[7];
  const float* Wf = (const float*)d_in[8];
  const float* bf = (const float*)d_in[9];
  const float* W1 = (const float*)d_in[10];
  const float* b1 = (const float*)d_in[11];
  const float* W2 = (const float*)d_in[12];
  const float* b2 = (const float*)d_in[13];
  const float* W3 = (const float*)d_in[14];
  const float* b3 = (const float*)d_in[15];
  float* outp = (float*)d_out;

  char* ws = (char*)d_ws;
  const size_t MB = 1ull << 20;
  // Region A [0,64M): scores f32; after softmax reused as vp/vpt/outb/h1/h2
  float* scores = (float*)ws;
  f16*  vp   = (f16*)ws;
  f16*  vpt  = (f16*)(ws + 16 * MB);
  f16*  outb = (f16*)(ws + 32 * MB);
  f16*  h1b  = (f16*)ws;
  f16*  h2b  = (f16*)(ws + 16 * MB);
  // [64M,96M): q16+k16, reused as softmax weights after scores GEMM
  f16*  q16  = (f16*)(ws + 64 * MB);
  f16*  wts  = (f16*)(ws + 64 * MB);
  f16*  k16  = (f16*)(ws + 80 * MB);
  f16*  v16  = (f16*)(ws + 96 * MB);
  char* cst  = ws + 112 * MB;
  f16*  Wv16 = (f16*)(cst);
  f16*  W116 = (f16*)(cst + 512 * 1024);
  f16*  W216 = (f16*)(cst + 1024 * 1024);
  float* dv   = (float*)(cst + 1280 * 1024);
  float* wfb  = (float*)(cst + 1312 * 1024);
  float* h1d  = (float*)(cst + 1376 * 1024);
  float* h2d  = (float*)(cst + 1408 * 1024);
  unsigned* mm = (unsigned*)(cst + 1424 * 1024);
  float* fbws  = (float*)(cst + 1424 * 1024 + 64);

  init_count<<<1, 256, 0, stream>>>((const unsigned char*)mask, mm);

  f32_to_f16_k<<<8192, 256, 0, stream>>>(q,  q16, 2097152);
  f32_to_f16_k<<<8192, 256, 0, stream>>>(kk, k16, 2097152);
  f32_to_f16_k<<<8192, 256, 0, stream>>>(v,  v16, 2097152);
  f32_to_f16_k<<<256, 256, 0, stream>>>(Wv, Wv16, 65536);
  f32_to_f16_k<<<256, 256, 0, stream>>>(W1, W116, 65536);
  f32_to_f16_k<<<128, 256, 0, stream>>>(W2, W216, 32768);

  dv_kernel<<<32, 256, 0, stream>>>(uq, Wf, bf, dv);

  // scores = q @ k^T / sqrt(512), f32 out + global min/max
  gemm_bt<EPI_SCORES><<<dim3(8, 8, 16), 256, 0, stream>>>(
      q16, k16, scores, 512, 512, 1024, 512,
      524288LL, 524288LL, 1048576LL,
      nullptr, 0.04419417382415922f, mm, nullptr, nullptr);

  fb_kernel<<<1, 1, 0, stream>>>(fallback, mm, fbws);

  softmax_rows<<<16384, 256, 0, stream>>>(scores, mask, fbws, mm + 3, wts, wfb);

  // vp = v @ Wv^T + bv (f16 out)
  gemm_bt<EPI_BIAS><<<dim3(4, 128, 1), 256, 0, stream>>>(
      v16, Wv16, vp, 512, 512, 512, 512, 0LL, 0LL, 0LL,
      bv, 1.f, nullptr, nullptr, nullptr);

  transpose_k<<<dim3(8, 16, 16), 256, 0, stream>>>(vp, vpt);

  // out = weights @ vp + wfb*dv (f16 out)
  gemm_bt<EPI_OUT><<<dim3(4, 8, 16), 256, 0, stream>>>(
      wts, vpt, outb, 1024, 1024, 512, 1024,
      1048576LL, 524288LL, 524288LL,
      nullptr, 1.f, nullptr, wfb, dv);

  // h1 = relu(out @ W1^T + b1)
  gemm_bt<EPI_RELU><<<dim3(4, 128, 1), 256, 0, stream>>>(
      outb, W116, h1b, 512, 512, 512, 512, 0LL, 0LL, 0LL,
      b1, 1.f, nullptr, nullptr, nullptr);

  // h2 = relu(h1 @ W2^T + b2)
  gemm_bt<EPI_RELU><<<dim3(2, 128, 1), 256, 0, stream>>>(
      h1b, W216, h2b, 512, 512, 256, 512, 0LL, 0LL, 0LL,
      b2, 1.f, nullptr, nullptr, nullptr);

  y_kernel<<<1024, 256, 0, stream>>>(h2b, W3, b3, outp);

  // default-values scorer branch (f32 end-to-end)
  fc_relu_k<<<32, 256, 0, stream>>>(dv, W1, b1, h1d, 512, 512);
  fc_relu_k<<<16, 256, 0, stream>>>(h1d, W2, b2, h2d, 512, 256);
  fc3_k<<<1, 64, 0, stream>>>(h2d, W3, b3, outp + 16384);

  (void)in_sizes; (void)n_in; (void)out_size; (void)ws_size;
}

// Round 2
// 424.165 us; speedup vs baseline: 1.0596x; 1.0596x over previous
//
#include <hip/hip_runtime.h>

typedef _Float16 f16;
typedef f16  f16x8 __attribute__((ext_vector_type(8)));
typedef f16  f16x4 __attribute__((ext_vector_type(4)));
typedef float f32x4 __attribute__((ext_vector_type(4)));

__device__ __forceinline__ void gld_lds16(const f16* g, void* l) {
  __builtin_amdgcn_global_load_lds((const __attribute__((address_space(1))) void*)g,
                                   (__attribute__((address_space(3))) void*)l,
                                   16, 0, 0);
}

__device__ __forceinline__ unsigned encf(float x) {
  unsigned u = __float_as_uint(x);
  return (u & 0x80000000u) ? ~u : (u | 0x80000000u);
}
__device__ __forceinline__ float decf(unsigned e) {
  unsigned u = (e & 0x80000000u) ? (e ^ 0x80000000u) : ~e;
  return __uint_as_float(u);
}

enum { EPI_SCORES = 0, EPI_BIAS = 1, EPI_RELU = 2, EPI_OUT = 3, EPI_BIASR = 4 };

// C[M,N] = A[M,K] @ B[N,K]^T, 128x128 tile, BK=32, 4 waves (2x2), 16x16x32 f16 MFMA.
// Double-buffered LDS: issue next-tile global_load_lds BEFORE compute of current tile.
template<int EPI>
__global__ __launch_bounds__(256)
void gemm_bt(const f16* __restrict__ A, const f16* __restrict__ B, void* __restrict__ C,
             int lda, int ldb, int ldc, int K,
             long long sA, long long sB, long long sC,
             const float* __restrict__ bias, float scale,
             unsigned* __restrict__ mm,
             const float* __restrict__ wfb, const float* __restrict__ dvv)
{
  __shared__ __align__(16) f16 As[2][128][32];
  __shared__ __align__(16) f16 Bs[2][128][32];
  const int tid  = threadIdx.x;
  const int lane = tid & 63;
  const int w    = tid >> 6;
  const int wm   = w >> 1, wn = w & 1;
  const int z    = blockIdx.z;
  const int m0   = blockIdx.y * 128, n0 = blockIdx.x * 128;
  const f16* Ab = A + (size_t)z * sA + (size_t)m0 * lda;
  const f16* Bb = B + (size_t)z * sB + (size_t)n0 * ldb;

  f32x4 acc[4][4] = {};

  const int nsteps = K >> 5;

  // stage K-tile `ks` into buffer `buf`
#define STAGE(buf, ks)                                                            \
  {                                                                               \
    const int k0_ = (ks) * 32;                                                    \
    _Pragma("unroll")                                                             \
    for (int i = 0; i < 2; ++i) {                                                 \
      const int ci = i * 256 + tid;                                               \
      const int r  = ci >> 2;                                                     \
      const int sg = ci & 3;                                                      \
      gld_lds16(Ab + (size_t)r * lda + k0_ + sg * 8,                              \
                (char*)As + (size_t)(buf) * 8192 + (size_t)(i * 256 + w * 64) * 16); \
      gld_lds16(Bb + (size_t)r * ldb + k0_ + sg * 8,                              \
                (char*)Bs + (size_t)(buf) * 8192 + (size_t)(i * 256 + w * 64) * 16); \
    }                                                                             \
  }

  STAGE(0, 0)
  __syncthreads();

  int cur = 0;
  for (int t = 0; t < nsteps; ++t) {
    if (t + 1 < nsteps) STAGE(cur ^ 1, t + 1)
    f16x8 af[4], bfr[4];
#pragma unroll
    for (int m = 0; m < 4; ++m)
      af[m] = *(const f16x8*)&As[cur][wm * 64 + m * 16 + (lane & 15)][(lane >> 4) * 8];
#pragma unroll
    for (int n = 0; n < 4; ++n)
      bfr[n] = *(const f16x8*)&Bs[cur][wn * 64 + n * 16 + (lane & 15)][(lane >> 4) * 8];
#pragma unroll
    for (int m = 0; m < 4; ++m)
#pragma unroll
      for (int n = 0; n < 4; ++n)
        acc[m][n] = __builtin_amdgcn_mfma_f32_16x16x32_f16(af[m], bfr[n], acc[m][n], 0, 0, 0);
    __syncthreads();
    cur ^= 1;
  }
#undef STAGE

  const int col_l = lane & 15;
  const int row_l = (lane >> 4) << 2;

  if constexpr (EPI == EPI_SCORES) {
    float* Cf = (float*)C + (size_t)z * sC + (size_t)m0 * ldc + n0;
    float lmax = -3.402823466e38f, lmin = 3.402823466e38f;
#pragma unroll
    for (int m = 0; m < 4; ++m)
#pragma unroll
      for (int n = 0; n < 4; ++n)
#pragma unroll
        for (int r = 0; r < 4; ++r) {
          float val = acc[m][n][r] * scale;
          lmax = fmaxf(lmax, val); lmin = fminf(lmin, val);
          Cf[(size_t)(wm * 64 + m * 16 + row_l + r) * ldc + (wn * 64 + n * 16 + col_l)] = val;
        }
#pragma unroll
    for (int off = 32; off >= 1; off >>= 1) {
      lmax = fmaxf(lmax, __shfl_xor(lmax, off));
      lmin = fminf(lmin, __shfl_xor(lmin, off));
    }
    if (lane == 0) {
      atomicMax(&mm[0], encf(lmax));
      atomicMin(&mm[1], encf(lmin));
    }
  } else {
    f16* Ch = (f16*)C + (size_t)z * sC + (size_t)m0 * ldc + n0;
#pragma unroll
    for (int m = 0; m < 4; ++m)
#pragma unroll
      for (int n = 0; n < 4; ++n)
#pragma unroll
        for (int r = 0; r < 4; ++r) {
          const int rr = wm * 64 + m * 16 + row_l + r;
          const int cc = wn * 64 + n * 16 + col_l;
          float val = acc[m][n][r];
          if constexpr (EPI == EPI_BIAS || EPI == EPI_RELU) val += bias[n0 + cc];
          if constexpr (EPI == EPI_BIASR) val += bias[m0 + rr];
          if constexpr (EPI == EPI_RELU) val = fmaxf(val, 0.0f);
          if constexpr (EPI == EPI_OUT)
            val += wfb[z * 1024 + m0 + rr] * dvv[z * 512 + n0 + cc];
          Ch[(size_t)rr * ldc + cc] = (f16)val;
        }
  }
}

// fused f32->f16 convert of q,k,v (equal sizes, n4each float4 chunks each)
__global__ __launch_bounds__(256)
void conv3_k(const float* __restrict__ a, const float* __restrict__ b,
             const float* __restrict__ c,
             f16* __restrict__ oa, f16* __restrict__ ob, f16* __restrict__ oc,
             int n4each)
{
  int i = blockIdx.x * 256 + threadIdx.x;
  int seg = i / n4each;
  int j = i - seg * n4each;
  const float* src = (seg == 0) ? a : ((seg == 1) ? b : c);
  f16* dst = (seg == 0) ? oa : ((seg == 1) ? ob : oc);
  float4 v = *(const float4*)(src + (size_t)j * 4);
  f16x4 o = { (f16)v.x, (f16)v.y, (f16)v.z, (f16)v.w };
  *(f16x4*)(dst + (size_t)j * 4) = o;
}

// fused weight converts: Wv (64K f4) + W1 (64K f4) + W2 (32K f4)
__global__ __launch_bounds__(256)
void convw_k(const float* __restrict__ wv, const float* __restrict__ w1,
             const float* __restrict__ w2,
             f16* __restrict__ owv, f16* __restrict__ ow1, f16* __restrict__ ow2)
{
  int i = blockIdx.x * 256 + threadIdx.x;   // 0..163839
  const float* src; f16* dst; int j;
  if (i < 65536)       { src = wv; dst = owv; j = i; }
  else if (i < 131072) { src = w1; dst = ow1; j = i - 65536; }
  else                 { src = w2; dst = ow2; j = i - 131072; }
  float4 v = *(const float4*)(src + (size_t)j * 4);
  f16x4 o = { (f16)v.x, (f16)v.y, (f16)v.z, (f16)v.w };
  *(f16x4*)(dst + (size_t)j * 4) = o;
}

// one block: count nonzero bytes of mask (dtype sniffing) + init min/max atomics
__global__ void init_count(const unsigned char* __restrict__ mask, unsigned* __restrict__ mm)
{
  __shared__ int red[256];
  int c = 0;
  for (int i = threadIdx.x; i < 16384; i += 256) c += (mask[i] != 0) ? 1 : 0;
  red[threadIdx.x] = c;
  __syncthreads();
  for (int s = 128; s > 0; s >>= 1) {
    if (threadIdx.x < s) red[threadIdx.x] += red[threadIdx.x + s];
    __syncthreads();
  }
  if (threadIdx.x == 0) {
    mm[0] = 0u;            // max encode accumulator
    mm[1] = 0xFFFFFFFFu;   // min encode accumulator
    mm[2] = (unsigned)red[0];
  }
}

__global__ __launch_bounds__(256)
void softmax_rows(const float* __restrict__ scores, const void* __restrict__ maskp,
                  const float* __restrict__ fallback, const unsigned* __restrict__ mm,
                  f16* __restrict__ Wt, float* __restrict__ wfb)
{
  __shared__ float red[8];
  const int row  = blockIdx.x;
  const int b    = row >> 10;
  const int tid  = threadIdx.x;
  const int lane = tid & 63, w = tid >> 6;
  const float fb = 0.99f * fallback[0] + 0.01f * 0.5f * (decf(mm[0]) + decf(mm[1]));
  const unsigned mode = (mm[2] > 5000u) ? 1u : 0u;
  const float* s = scores + (size_t)row * 1024;
  const int k0 = tid * 4;
  float4 v = *(const float4*)(s + k0);
  float x[4];
  if (mode) {
    const unsigned char* m8 = (const unsigned char*)maskp + b * 1024 + k0;
    x[0] = m8[0] ? -1e9f : v.x;  x[1] = m8[1] ? -1e9f : v.y;
    x[2] = m8[2] ? -1e9f : v.z;  x[3] = m8[3] ? -1e9f : v.w;
  } else {
    const int* mi = (const int*)maskp + b * 1024 + k0;
    x[0] = mi[0] ? -1e9f : v.x;  x[1] = mi[1] ? -1e9f : v.y;
    x[2] = mi[2] ? -1e9f : v.z;  x[3] = mi[3] ? -1e9f : v.w;
  }
  float mx = fmaxf(fmaxf(x[0], x[1]), fmaxf(x[2], x[3]));
#pragma unroll
  for (int off = 32; off >= 1; off >>= 1) mx = fmaxf(mx, __shfl_xor(mx, off));
  if (lane == 0) red[w] = mx;
  __syncthreads();
  mx = fmaxf(fmaxf(fmaxf(red[0], red[1]), fmaxf(red[2], red[3])), fb);
  float e0 = expf(x[0] - mx), e1 = expf(x[1] - mx), e2 = expf(x[2] - mx), e3 = expf(x[3] - mx);
  float sum = (e0 + e1) + (e2 + e3);
#pragma unroll
  for (int off = 32; off >= 1; off >>= 1) sum += __shfl_xor(sum, off);
  if (lane == 0) red[4 + w] = sum;
  __syncthreads();
  float efb = expf(fb - mx);
  float Z = ((red[4] + red[5]) + (red[6] + red[7])) + efb;
  float inv = 1.0f / Z;
  f16x4 o = { (f16)(e0 * inv), (f16)(e1 * inv), (f16)(e2 * inv), (f16)(e3 * inv) };
  *(f16x4*)&Wt[(size_t)row * 1024 + k0] = o;
  if (tid == 0) wfb[row] = efb * inv;
}

__global__ void dv_kernel(const float* __restrict__ uq, const float* __restrict__ Wf,
                          const float* __restrict__ bfv, float* __restrict__ dv)
{
  int t = blockIdx.x * 256 + threadIdx.x;   // 0..8191
  int b = t >> 9, j = t & 511;
  const float4* x  = (const float4*)(uq + b * 512);
  const float4* wr = (const float4*)(Wf + (size_t)j * 512);
  float s = 0.f;
  for (int d = 0; d < 128; ++d) {
    float4 a = x[d], bw = wr[d];
    s += a.x * bw.x + a.y * bw.y + a.z * bw.z + a.w * bw.w;
  }
  dv[t] = s + bfv[j];
}

__global__ void fc_relu_k(const float* __restrict__ X, const float* __restrict__ Wm,
                          const float* __restrict__ bb, float* __restrict__ Y,
                          int In, int OutN)
{
  int t = blockIdx.x * 256 + threadIdx.x;
  int b = t / OutN, j = t - b * OutN;
  const float* x  = X + b * In;
  const float* wr = Wm + (size_t)j * In;
  float s = 0.f;
  for (int d = 0; d < In; ++d) s += x[d] * wr[d];
  Y[t] = fmaxf(s + bb[j], 0.f);
}

__global__ void fc3_k(const float* __restrict__ h2d, const float* __restrict__ W3,
                      const float* __restrict__ b3, float* __restrict__ outp)
{
  int b = threadIdx.x;
  if (b < 16) {
    const float* x = h2d + b * 256;
    float s = 0.f;
    for (int d = 0; d < 256; ++d) s += x[d] * W3[d];
    outp[b] = tanhf(s + b3[0]);
  }
}

__global__ __launch_bounds__(256)
void y_kernel(const f16* __restrict__ h2, const float* __restrict__ W3,
              const float* __restrict__ b3, float* __restrict__ outp)
{
  int row = blockIdx.x * 16 + (threadIdx.x >> 4);
  int l   = threadIdx.x & 15;
  const f16* h = h2 + (size_t)row * 256 + l * 16;
  float s = 0.f;
#pragma unroll
  for (int j = 0; j < 16; ++j) s += (float)h[j] * W3[l * 16 + j];
#pragma unroll
  for (int off = 1; off < 16; off <<= 1) s += __shfl_xor(s, off);
  if (l == 0) outp[row] = tanhf(s + b3[0]);
}

extern "C" void kernel_launch(void* const* d_in, const int* in_sizes, int n_in,
                              void* d_out, int out_size, void* d_ws, size_t ws_size,
                              hipStream_t stream) {
  const float* uq       = (const float*)d_in[0];
  const float* q        = (const float*)d_in[1];
  const float* kk       = (const float*)d_in[2];
  const float* v        = (const float*)d_in[3];
  const void*  mask     = d_in[4];
  const float* fallback = (const float*)d_in[5];
  const float* Wv = (const float*)d_in[6];
  const float* bv = (const float*)d_in[7];
  const float* Wf = (const float*)d_in[8];
  const float* bf = (const float*)d_in[9];
  const float* W1 = (const float*)d_in[10];
  const float* b1 = (const float*)d_in[11];
  const float* W2 = (const float*)d_in[12];
  const float* b2 = (const float*)d_in[13];
  const float* W3 = (const float*)d_in[14];
  const float* b3 = (const float*)d_in[15];
  float* outp = (float*)d_out;

  char* ws = (char*)d_ws;
  const size_t MB = 1ull << 20;
  // Region A [0,64M): scores f32; after softmax reused as vpt/outb/h1/h2
  float* scores = (float*)ws;
  f16*  vpt  = (f16*)(ws + 16 * MB);
  f16*  outb = (f16*)(ws + 32 * MB);
  f16*  h1b  = (f16*)ws;
  f16*  h2b  = (f16*)(ws + 48 * MB);
  // [64M,112M): q16+k16+v16; q16 reused as softmax weights after scores GEMM
  f16*  q16  = (f16*)(ws + 64 * MB);
  f16*  wts  = (f16*)(ws + 64 * MB);
  f16*  k16  = (f16*)(ws + 80 * MB);
  f16*  v16  = (f16*)(ws + 96 * MB);
  char* cst  = ws + 112 * MB;
  f16*  Wv16 = (f16*)(cst);
  f16*  W116 = (f16*)(cst + 512 * 1024);
  f16*  W216 = (f16*)(cst + 1024 * 1024);
  float* dv   = (float*)(cst + 1280 * 1024);
  float* wfb  = (float*)(cst + 1312 * 1024);
  float* h1d  = (float*)(cst + 1376 * 1024);
  float* h2d  = (float*)(cst + 1408 * 1024);
  unsigned* mm = (unsigned*)(cst + 1424 * 1024);

  init_count<<<1, 256, 0, stream>>>((const unsigned char*)mask, mm);

  conv3_k<<<24576, 256, 0, stream>>>(q, kk, v, q16, k16, v16, 2097152);
  convw_k<<<640, 256, 0, stream>>>(Wv, W1, W2, Wv16, W116, W216);

  dv_kernel<<<32, 256, 0, stream>>>(uq, Wf, bf, dv);

  // scores = q @ k^T / sqrt(512), f32 out + global min/max
  gemm_bt<EPI_SCORES><<<dim3(8, 8, 16), 256, 0, stream>>>(
      q16, k16, scores, 512, 512, 1024, 512,
      524288LL, 524288LL, 1048576LL,
      nullptr, 0.04419417382415922f, mm, nullptr, nullptr);

  softmax_rows<<<16384, 256, 0, stream>>>(scores, mask, fallback, mm, wts, wfb);

  // vpt[d][k] = sum_e Wv[d][e] v[k][e] + bv[d]  (= (v @ Wv^T)^T, transposed directly)
  gemm_bt<EPI_BIASR><<<dim3(8, 4, 16), 256, 0, stream>>>(
      Wv16, v16, vpt, 512, 512, 1024, 512,
      0LL, 524288LL, 524288LL,
      bv, 1.f, nullptr, nullptr, nullptr);

  // out = weights @ vp + wfb*dv (f16 out)
  gemm_bt<EPI_OUT><<<dim3(4, 8, 16), 256, 0, stream>>>(
      wts, vpt, outb, 1024, 1024, 512, 1024,
      1048576LL, 524288LL, 524288LL,
      nullptr, 1.f, nullptr, wfb, dv);

  // h1 = relu(out @ W1^T + b1)
  gemm_bt<EPI_RELU><<<dim3(4, 128, 1), 256, 0, stream>>>(
      outb, W116, h1b, 512, 512, 512, 512, 0LL, 0LL, 0LL,
      b1, 1.f, nullptr, nullptr, nullptr);

  // h2 = relu(h1 @ W2^T + b2)
  gemm_bt<EPI_RELU><<<dim3(2, 128, 1), 256, 0, stream>>>(
      h1b, W216, h2b, 512, 512, 256, 512, 0LL, 0LL, 0LL,
      b2, 1.f, nullptr, nullptr, nullptr);

  y_kernel<<<1024, 256, 0, stream>>>(h2b, W3, b3, outp);

  // default-values scorer branch (f32 end-to-end)
  fc_relu_k<<<32, 256, 0, stream>>>(dv, W1, b1, h1d, 512, 512);
  fc_relu_k<<<16, 256, 0, stream>>>(h1d, W2, b2, h2d, 512, 256);
  fc3_k<<<1, 64, 0, stream>>>(h2d, W3, b3, outp + 16384);

  (void)in_sizes; (void)n_in; (void)out_size; (void)ws_size;
}

// Round 3
// 337.716 us; speedup vs baseline: 1.3309x; 1.2560x over previous
//
#include <hip/hip_runtime.h>

typedef _Float16 f16;
typedef f16  f16x8 __attribute__((ext_vector_type(8)));
typedef f16  f16x4 __attribute__((ext_vector_type(4)));
typedef float f32x4 __attribute__((ext_vector_type(4)));

__device__ __forceinline__ void gld_lds16(const f16* g, void* l) {
  __builtin_amdgcn_global_load_lds((const __attribute__((address_space(1))) void*)g,
                                   (__attribute__((address_space(3))) void*)l,
                                   16, 0, 0);
}

enum { EPI_SCORES = 0, EPI_RELU = 2, EPI_OUT = 3, EPI_BIASR = 4 };

// C[M,N] = A[M,K] @ B[N,K]^T, 128x128 tile, BK=32, 4 waves (2x2), 16x16x32 f16 MFMA.
// 3-stage LDS pipeline, counted vmcnt (never 0 mid-loop), raw s_barrier, swizzled LDS.
// XMAP: group blocks of one batch (z) onto one XCD for L2 locality (nz % 8 == 0).
template<int EPI, bool XMAP>
__global__ __launch_bounds__(256)
void gemm_bt(const f16* __restrict__ A, const f16* __restrict__ B, void* __restrict__ C,
             int lda, int ldb, int ldc, int K,
             long long sA, long long sB, long long sC,
             const float* __restrict__ bias, float scale,
             float* __restrict__ mmarr, int nmm,
             const float* __restrict__ wfb, const float* __restrict__ dvv,
             int nx, int nbz)
{
  __shared__ __align__(16) f16 As[3][128][32];
  __shared__ __align__(16) f16 Bs[3][128][32];
  __shared__ float redm[4], redn[4];
  const int tid  = threadIdx.x;
  const int lane = tid & 63;
  const int w    = tid >> 6;
  const int wm   = w >> 1, wn = w & 1;

  const int lin = blockIdx.x;
  int bz, bj;
  if constexpr (XMAP) {
    const int xcd = lin & 7, rest = lin >> 3;
    const int grp = rest / nbz;
    bj = rest - grp * nbz;
    bz = xcd + (grp << 3);
  } else {
    bz = lin / nbz; bj = lin - bz * nbz;
  }
  const int m0 = (bj / nx) * 128, n0 = (bj % nx) * 128;
  const f16* Ab = A + (size_t)bz * sA + (size_t)m0 * lda;
  const f16* Bb = B + (size_t)bz * sB + (size_t)n0 * ldb;

  f32x4 acc[4][4] = {};
  const int nsteps = K >> 5;

  // stage K-tile `ks` into buffer byte-offset `bufb`; source seg XOR-swizzled so the
  // linear LDS write + swizzled ds_read form the same involution (rule #21).
#define STAGE(bufb, ks)                                                              \
  {                                                                                  \
    const int k0_ = (ks) << 5;                                                       \
    _Pragma("unroll")                                                                \
    for (int i = 0; i < 2; ++i) {                                                    \
      const int ci = i * 256 + tid;                                                  \
      const int r  = ci >> 2;                                                        \
      const int sg = (ci & 3) ^ ((r >> 1) & 3);                                      \
      gld_lds16(Ab + (size_t)r * lda + k0_ + sg * 8,                                 \
                (char*)As + (bufb) + (size_t)(i * 256 + w * 64) * 16);               \
      gld_lds16(Bb + (size_t)r * ldb + k0_ + sg * 8,                                 \
                (char*)Bs + (bufb) + (size_t)(i * 256 + w * 64) * 16);               \
    }                                                                                \
  }

  STAGE(0, 0)
  STAGE(8192, 1)

  // swizzled element offset within a row for this lane's k-segment
  const int elemoff = (((lane >> 4) ^ ((lane >> 1) & 3)) << 3);

  int cur = 0;
  for (int t = 0; t < nsteps; ++t) {
    if (t + 1 < nsteps) asm volatile("s_waitcnt vmcnt(4)" ::: "memory");
    else                asm volatile("s_waitcnt vmcnt(0)" ::: "memory");
    __builtin_amdgcn_s_barrier();
    __builtin_amdgcn_sched_barrier(0);
    int st = cur + 2; if (st >= 3) st -= 3;
    if (t + 2 < nsteps) STAGE(st * 8192, t + 2)
    f16x8 af[4], bfr[4];
#pragma unroll
    for (int m = 0; m < 4; ++m)
      af[m] = *(const f16x8*)&As[cur][wm * 64 + m * 16 + (lane & 15)][elemoff];
#pragma unroll
    for (int n = 0; n < 4; ++n)
      bfr[n] = *(const f16x8*)&Bs[cur][wn * 64 + n * 16 + (lane & 15)][elemoff];
    __builtin_amdgcn_s_setprio(1);
#pragma unroll
    for (int m = 0; m < 4; ++m)
#pragma unroll
      for (int n = 0; n < 4; ++n)
        acc[m][n] = __builtin_amdgcn_mfma_f32_16x16x32_f16(af[m], bfr[n], acc[m][n], 0, 0, 0);
    __builtin_amdgcn_s_setprio(0);
    cur = (cur + 1 == 3) ? 0 : cur + 1;
  }
#undef STAGE

  const int col_l = lane & 15;
  const int row_l = (lane >> 4) << 2;

  if constexpr (EPI == EPI_SCORES) {
    f16* Ch = (f16*)C + (size_t)bz * sC + (size_t)m0 * ldc + n0;
    float lmax = -3.402823466e38f, lmin = 3.402823466e38f;
#pragma unroll
    for (int m = 0; m < 4; ++m)
#pragma unroll
      for (int n = 0; n < 4; ++n)
#pragma unroll
        for (int r = 0; r < 4; ++r) {
          float val = acc[m][n][r] * scale;
          lmax = fmaxf(lmax, val); lmin = fminf(lmin, val);
          Ch[(size_t)(wm * 64 + m * 16 + row_l + r) * ldc + (wn * 64 + n * 16 + col_l)] = (f16)val;
        }
#pragma unroll
    for (int off = 32; off >= 1; off >>= 1) {
      lmax = fmaxf(lmax, __shfl_xor(lmax, off));
      lmin = fminf(lmin, __shfl_xor(lmin, off));
    }
    if (lane == 0) { redm[w] = lmax; redn[w] = lmin; }
    __syncthreads();
    if (tid == 0) {
      mmarr[lin]       = fmaxf(fmaxf(redm[0], redm[1]), fmaxf(redm[2], redm[3]));
      mmarr[nmm + lin] = fminf(fminf(redn[0], redn[1]), fminf(redn[2], redn[3]));
    }
  } else {
    f16* Ch = (f16*)C + (size_t)bz * sC + (size_t)m0 * ldc + n0;
#pragma unroll
    for (int m = 0; m < 4; ++m)
#pragma unroll
      for (int n = 0; n < 4; ++n)
#pragma unroll
        for (int r = 0; r < 4; ++r) {
          const int rr = wm * 64 + m * 16 + row_l + r;
          const int cc = wn * 64 + n * 16 + col_l;
          float val = acc[m][n][r];
          if constexpr (EPI == EPI_RELU) { val += bias[n0 + cc]; val = fmaxf(val, 0.0f); }
          if constexpr (EPI == EPI_BIASR) val += bias[m0 + rr];
          if constexpr (EPI == EPI_OUT)
            val += wfb[bz * 1024 + m0 + rr] * dvv[bz * 512 + n0 + cc];
          Ch[(size_t)rr * ldc + cc] = (f16)val;
        }
  }
}

// reduce per-block max/min -> fb scalar
__global__ __launch_bounds__(256)
void reduce_mm(const float* __restrict__ mmarr, int n,
               const float* __restrict__ fallback, float* __restrict__ fbv)
{
  __shared__ float rm[4], rn[4];
  const int lane = threadIdx.x & 63, w = threadIdx.x >> 6;
  float mx = -3.402823466e38f, mn = 3.402823466e38f;
  for (int i = threadIdx.x; i < n; i += 256) {
    mx = fmaxf(mx, mmarr[i]);
    mn = fminf(mn, mmarr[n + i]);
  }
#pragma unroll
  for (int off = 32; off >= 1; off >>= 1) {
    mx = fmaxf(mx, __shfl_xor(mx, off));
    mn = fminf(mn, __shfl_xor(mn, off));
  }
  if (lane == 0) { rm[w] = mx; rn[w] = mn; }
  __syncthreads();
  if (threadIdx.x == 0) {
    float gmax = fmaxf(fmaxf(rm[0], rm[1]), fmaxf(rm[2], rm[3]));
    float gmin = fminf(fminf(rn[0], rn[1]), fminf(rn[2], rn[3]));
    fbv[0] = 0.99f * fallback[0] + 0.005f * (gmax + gmin);
  }
}

// fused f32->f16 convert of q,k,v
__global__ __launch_bounds__(256)
void conv3_k(const float* __restrict__ a, const float* __restrict__ b,
             const float* __restrict__ c,
             f16* __restrict__ oa, f16* __restrict__ ob, f16* __restrict__ oc,
             int n4each)
{
  int i = blockIdx.x * 256 + threadIdx.x;
  int seg = i / n4each;
  int j = i - seg * n4each;
  const float* src = (seg == 0) ? a : ((seg == 1) ? b : c);
  f16* dst = (seg == 0) ? oa : ((seg == 1) ? ob : oc);
  float4 v = *(const float4*)(src + (size_t)j * 4);
  f16x4 o = { (f16)v.x, (f16)v.y, (f16)v.z, (f16)v.w };
  *(f16x4*)(dst + (size_t)j * 4) = o;
}

__global__ __launch_bounds__(256)
void convw_k(const float* __restrict__ wv, const float* __restrict__ w1,
             const float* __restrict__ w2,
             f16* __restrict__ owv, f16* __restrict__ ow1, f16* __restrict__ ow2)
{
  int i = blockIdx.x * 256 + threadIdx.x;   // 0..163839
  const float* src; f16* dst; int j;
  if (i < 65536)       { src = wv; dst = owv; j = i; }
  else if (i < 131072) { src = w1; dst = ow1; j = i - 65536; }
  else                 { src = w2; dst = ow2; j = i - 131072; }
  float4 v = *(const float4*)(src + (size_t)j * 4);
  f16x4 o = { (f16)v.x, (f16)v.y, (f16)v.z, (f16)v.w };
  *(f16x4*)(dst + (size_t)j * 4) = o;
}

// one block: count nonzero bytes of mask (dtype sniffing)
__global__ void init_count(const unsigned char* __restrict__ mask, unsigned* __restrict__ mm)
{
  __shared__ int red[256];
  int c = 0;
  for (int i = threadIdx.x; i < 16384; i += 256) c += (mask[i] != 0) ? 1 : 0;
  red[threadIdx.x] = c;
  __syncthreads();
  for (int s = 128; s > 0; s >>= 1) {
    if (threadIdx.x < s) red[threadIdx.x] += red[threadIdx.x + s];
    __syncthreads();
  }
  if (threadIdx.x == 0) mm[0] = (unsigned)red[0];
}

__global__ __launch_bounds__(256)
void softmax_rows(const f16* __restrict__ scores, const void* __restrict__ maskp,
                  const float* __restrict__ fbv, const unsigned* __restrict__ mm,
                  f16* __restrict__ Wt, float* __restrict__ wfb)
{
  __shared__ float red[8];
  const int row  = blockIdx.x;
  const int b    = row >> 10;
  const int tid  = threadIdx.x;
  const int lane = tid & 63, w = tid >> 6;
  const float fb = fbv[0];
  const unsigned mode = (mm[0] > 5000u) ? 1u : 0u;
  const f16* s = scores + (size_t)row * 1024;
  const int k0 = tid * 4;
  f16x4 sv = *(const f16x4*)(s + k0);
  float x[4];
  if (mode) {
    const unsigned char* m8 = (const unsigned char*)maskp + b * 1024 + k0;
    x[0] = m8[0] ? -1e9f : (float)sv[0];  x[1] = m8[1] ? -1e9f : (float)sv[1];
    x[2] = m8[2] ? -1e9f : (float)sv[2];  x[3] = m8[3] ? -1e9f : (float)sv[3];
  } else {
    const int* mi = (const int*)maskp + b * 1024 + k0;
    x[0] = mi[0] ? -1e9f : (float)sv[0];  x[1] = mi[1] ? -1e9f : (float)sv[1];
    x[2] = mi[2] ? -1e9f : (float)sv[2];  x[3] = mi[3] ? -1e9f : (float)sv[3];
  }
  float mx = fmaxf(fmaxf(x[0], x[1]), fmaxf(x[2], x[3]));
#pragma unroll
  for (int off = 32; off >= 1; off >>= 1) mx = fmaxf(mx, __shfl_xor(mx, off));
  if (lane == 0) red[w] = mx;
  __syncthreads();
  mx = fmaxf(fmaxf(fmaxf(red[0], red[1]), fmaxf(red[2], red[3])), fb);
  float e0 = expf(x[0] - mx), e1 = expf(x[1] - mx), e2 = expf(x[2] - mx), e3 = expf(x[3] - mx);
  float sum = (e0 + e1) + (e2 + e3);
#pragma unroll
  for (int off = 32; off >= 1; off >>= 1) sum += __shfl_xor(sum, off);
  if (lane == 0) red[4 + w] = sum;
  __syncthreads();
  float efb = expf(fb - mx);
  float Z = ((red[4] + red[5]) + (red[6] + red[7])) + efb;
  float inv = 1.0f / Z;
  f16x4 o = { (f16)(e0 * inv), (f16)(e1 * inv), (f16)(e2 * inv), (f16)(e3 * inv) };
  *(f16x4*)&Wt[(size_t)row * 1024 + k0] = o;
  if (tid == 0) wfb[row] = efb * inv;
}

__global__ void dv_kernel(const float* __restrict__ uq, const float* __restrict__ Wf,
                          const float* __restrict__ bfv, float* __restrict__ dv)
{
  int t = blockIdx.x * 256 + threadIdx.x;   // 0..8191
  int b = t >> 9, j = t & 511;
  const float4* x  = (const float4*)(uq + b * 512);
  const float4* wr = (const float4*)(Wf + (size_t)j * 512);
  float s = 0.f;
  for (int d = 0; d < 128; ++d) {
    float4 a = x[d], bw = wr[d];
    s += a.x * bw.x + a.y * bw.y + a.z * bw.z + a.w * bw.w;
  }
  dv[t] = s + bfv[j];
}

__global__ void fc_relu_k(const float* __restrict__ X, const float* __restrict__ Wm,
                          const float* __restrict__ bb, float* __restrict__ Y,
                          int In, int OutN)
{
  int t = blockIdx.x * 256 + threadIdx.x;
  int b = t / OutN, j = t - b * OutN;
  const float* x  = X + b * In;
  const float* wr = Wm + (size_t)j * In;
  float s = 0.f;
  for (int d = 0; d < In; ++d) s += x[d] * wr[d];
  Y[t] = fmaxf(s + bb[j], 0.f);
}

__global__ void fc3_k(const float* __restrict__ h2d, const float* __restrict__ W3,
                      const float* __restrict__ b3, float* __restrict__ outp)
{
  int b = threadIdx.x;
  if (b < 16) {
    const float* x = h2d + b * 256;
    float s = 0.f;
    for (int d = 0; d < 256; ++d) s += x[d] * W3[d];
    outp[b] = tanhf(s + b3[0]);
  }
}

__global__ __launch_bounds__(256)
void y_kernel(const f16* __restrict__ h2, const float* __restrict__ W3,
              const float* __restrict__ b3, float* __restrict__ outp)
{
  int row = blockIdx.x * 16 + (threadIdx.x >> 4);
  int l   = threadIdx.x & 15;
  const f16* h = h2 + (size_t)row * 256 + l * 16;
  float s = 0.f;
#pragma unroll
  for (int j = 0; j < 16; ++j) s += (float)h[j] * W3[l * 16 + j];
#pragma unroll
  for (int off = 1; off < 16; off <<= 1) s += __shfl_xor(s, off);
  if (l == 0) outp[row] = tanhf(s + b3[0]);
}

extern "C" void kernel_launch(void* const* d_in, const int* in_sizes, int n_in,
                              void* d_out, int out_size, void* d_ws, size_t ws_size,
                              hipStream_t stream) {
  const float* uq       = (const float*)d_in[0];
  const float* q        = (const float*)d_in[1];
  const float* kk       = (const float*)d_in[2];
  const float* v        = (const float*)d_in[3];
  const void*  mask     = d_in[4];
  const float* fallback = (const float*)d_in[5];
  const float* Wv = (const float*)d_in[6];
  const float* bv = (const float*)d_in[7];
  const float* Wf = (const float*)d_in[8];
  const float* bf = (const float*)d_in[9];
  const float* W1 = (const float*)d_in[10];
  const float* b1 = (const float*)d_in[11];
  const float* W2 = (const float*)d_in[12];
  const float* b2 = (const float*)d_in[13];
  const float* W3 = (const float*)d_in[14];
  const float* b3 = (const float*)d_in[15];
  float* outp = (float*)d_out;

  char* ws = (char*)d_ws;
  const size_t MB = 1ull << 20;
  // [0,32M): scores f16 (dead after softmax) -> h1b [0,16M), h2b [16,24M)
  f16*  scores = (f16*)ws;
  f16*  h1b  = (f16*)ws;
  f16*  h2b  = (f16*)(ws + 16 * MB);
  // [32,48M): vpt; [48,64M): outb
  f16*  vpt  = (f16*)(ws + 32 * MB);
  f16*  outb = (f16*)(ws + 48 * MB);
  // [64,112M): q16,k16,v16; wts reuses [64,96M) after scores GEMM
  f16*  q16  = (f16*)(ws + 64 * MB);
  f16*  wts  = (f16*)(ws + 64 * MB);
  f16*  k16  = (f16*)(ws + 80 * MB);
  f16*  v16  = (f16*)(ws + 96 * MB);
  char* cst  = ws + 112 * MB;
  f16*  Wv16 = (f16*)(cst);
  f16*  W116 = (f16*)(cst + 512 * 1024);
  f16*  W216 = (f16*)(cst + 1024 * 1024);
  float* dv   = (float*)(cst + 1280 * 1024);
  float* wfb  = (float*)(cst + 1312 * 1024);
  float* h1d  = (float*)(cst + 1376 * 1024);
  float* h2d  = (float*)(cst + 1408 * 1024);
  unsigned* mm = (unsigned*)(cst + 1424 * 1024);
  float* fbv   = (float*)(cst + 1428 * 1024);
  float* mmarr = (float*)(cst + 1432 * 1024);   // 2 * 1024 floats

  init_count<<<1, 256, 0, stream>>>((const unsigned char*)mask, mm);

  conv3_k<<<24576, 256, 0, stream>>>(q, kk, v, q16, k16, v16, 2097152);
  convw_k<<<640, 256, 0, stream>>>(Wv, W1, W2, Wv16, W116, W216);

  dv_kernel<<<32, 256, 0, stream>>>(uq, Wf, bf, dv);

  // scores = q @ k^T / sqrt(512) -> f16, per-block max/min
  gemm_bt<EPI_SCORES, true><<<1024, 256, 0, stream>>>(
      q16, k16, scores, 512, 512, 1024, 512,
      524288LL, 524288LL, 1048576LL,
      nullptr, 0.04419417382415922f, mmarr, 1024, nullptr, nullptr, 8, 64);

  reduce_mm<<<1, 256, 0, stream>>>(mmarr, 1024, fallback, fbv);

  softmax_rows<<<16384, 256, 0, stream>>>(scores, mask, fbv, mm, wts, wfb);

  // vpt[d][k] = sum_e Wv[d][e] v[k][e] + bv[d]
  gemm_bt<EPI_BIASR, true><<<512, 256, 0, stream>>>(
      Wv16, v16, vpt, 512, 512, 1024, 512,
      0LL, 524288LL, 524288LL,
      bv, 1.f, nullptr, 0, nullptr, nullptr, 8, 32);

  // out = weights @ vp + wfb*dv
  gemm_bt<EPI_OUT, true><<<512, 256, 0, stream>>>(
      wts, vpt, outb, 1024, 1024, 512, 1024,
      1048576LL, 524288LL, 524288LL,
      nullptr, 1.f, nullptr, 0, wfb, dv, 4, 32);

  // h1 = relu(out @ W1^T + b1)
  gemm_bt<EPI_RELU, false><<<512, 256, 0, stream>>>(
      outb, W116, h1b, 512, 512, 512, 512, 0LL, 0LL, 0LL,
      b1, 1.f, nullptr, 0, nullptr, nullptr, 4, 512);

  // h2 = relu(h1 @ W2^T + b2)
  gemm_bt<EPI_RELU, false><<<256, 256, 0, stream>>>(
      h1b, W216, h2b, 512, 512, 256, 512, 0LL, 0LL, 0LL,
      b2, 1.f, nullptr, 0, nullptr, nullptr, 2, 256);

  y_kernel<<<1024, 256, 0, stream>>>(h2b, W3, b3, outp);

  // default-values scorer branch (f32 end-to-end)
  fc_relu_k<<<32, 256, 0, stream>>>(dv, W1, b1, h1d, 512, 512);
  fc_relu_k<<<16, 256, 0, stream>>>(h1d, W2, b2, h2d, 512, 256);
  fc3_k<<<1, 64, 0, stream>>>(h2d, W3, b3, outp + 16384);

  (void)in_sizes; (void)n_in; (void)out_size; (void)ws_size;
}

// Round 4
// 190.903 us; speedup vs baseline: 2.3544x; 1.7690x over previous
//
#include <hip/hip_runtime.h>

typedef _Float16 f16;
typedef f16  f16x8 __attribute__((ext_vector_type(8)));
typedef f16  f16x4 __attribute__((ext_vector_type(4)));
typedef float f32x4 __attribute__((ext_vector_type(4)));

__device__ __forceinline__ void gld_lds16(const f16* g, void* l) {
  __builtin_amdgcn_global_load_lds((const __attribute__((address_space(1))) void*)g,
                                   (__attribute__((address_space(3))) void*)l,
                                   16, 0, 0);
}

enum { EPI_SCORES = 0, EPI_RELU = 2, EPI_OUT = 3, EPI_BIASR = 4 };

// C[M,N] = A[M,K] @ B[N,K]^T, 128x128 tile, BK=32, 4 waves (2x2), 16x16x32 f16 MFMA.
// 3-stage LDS pipeline, counted vmcnt (never 0 mid-loop), raw s_barrier, swizzled LDS.
// XMAP: group blocks of one batch (z) onto one XCD for L2 locality (nz % 8 == 0).
template<int EPI, bool XMAP>
__global__ __launch_bounds__(256)
void gemm_bt(const f16* __restrict__ A, const f16* __restrict__ B, void* __restrict__ C,
             int lda, int ldb, int ldc, int K,
             long long sA, long long sB, long long sC,
             const float* __restrict__ bias, float scale,
             float* __restrict__ mmarr, int nmm,
             const float* __restrict__ wfb, const float* __restrict__ dvv,
             int nx, int nbz)
{
  __shared__ __align__(16) f16 As[3][128][32];
  __shared__ __align__(16) f16 Bs[3][128][32];
  __shared__ float redm[4], redn[4];
  const int tid  = threadIdx.x;
  const int lane = tid & 63;
  const int w    = tid >> 6;
  const int wm   = w >> 1, wn = w & 1;

  const int lin = blockIdx.x;
  int bz, bj;
  if constexpr (XMAP) {
    const int xcd = lin & 7, rest = lin >> 3;
    const int grp = rest / nbz;
    bj = rest - grp * nbz;
    bz = xcd + (grp << 3);
  } else {
    bz = lin / nbz; bj = lin - bz * nbz;
  }
  const int m0 = (bj / nx) * 128, n0 = (bj % nx) * 128;
  const f16* Ab = A + (size_t)bz * sA + (size_t)m0 * lda;
  const f16* Bb = B + (size_t)bz * sB + (size_t)n0 * ldb;

  f32x4 acc[4][4] = {};
  const int nsteps = K >> 5;

  // stage K-tile `ks` into buffer byte-offset `bufb`; source seg XOR-swizzled so the
  // linear LDS write + swizzled ds_read form the same involution (rule #21).
#define STAGE(bufb, ks)                                                              \
  {                                                                                  \
    const int k0_ = (ks) << 5;                                                       \
    _Pragma("unroll")                                                                \
    for (int i = 0; i < 2; ++i) {                                                    \
      const int ci = i * 256 + tid;                                                  \
      const int r  = ci >> 2;                                                        \
      const int sg = (ci & 3) ^ ((r >> 1) & 3);                                      \
      gld_lds16(Ab + (size_t)r * lda + k0_ + sg * 8,                                 \
                (char*)As + (bufb) + (size_t)(i * 256 + w * 64) * 16);               \
      gld_lds16(Bb + (size_t)r * ldb + k0_ + sg * 8,                                 \
                (char*)Bs + (bufb) + (size_t)(i * 256 + w * 64) * 16);               \
    }                                                                                \
  }

  STAGE(0, 0)
  STAGE(8192, 1)

  // swizzled element offset within a row for this lane's k-segment
  const int elemoff = (((lane >> 4) ^ ((lane >> 1) & 3)) << 3);

  int cur = 0;
  for (int t = 0; t < nsteps; ++t) {
    if (t + 1 < nsteps) asm volatile("s_waitcnt vmcnt(4)" ::: "memory");
    else                asm volatile("s_waitcnt vmcnt(0)" ::: "memory");
    __builtin_amdgcn_s_barrier();
    __builtin_amdgcn_sched_barrier(0);
    int st = cur + 2; if (st >= 3) st -= 3;
    if (t + 2 < nsteps) STAGE(st * 8192, t + 2)
    f16x8 af[4], bfr[4];
#pragma unroll
    for (int m = 0; m < 4; ++m)
      af[m] = *(const f16x8*)&As[cur][wm * 64 + m * 16 + (lane & 15)][elemoff];
#pragma unroll
    for (int n = 0; n < 4; ++n)
      bfr[n] = *(const f16x8*)&Bs[cur][wn * 64 + n * 16 + (lane & 15)][elemoff];
    __builtin_amdgcn_s_setprio(1);
#pragma unroll
    for (int m = 0; m < 4; ++m)
#pragma unroll
      for (int n = 0; n < 4; ++n)
        acc[m][n] = __builtin_amdgcn_mfma_f32_16x16x32_f16(af[m], bfr[n], acc[m][n], 0, 0, 0);
    __builtin_amdgcn_s_setprio(0);
    cur = (cur + 1 == 3) ? 0 : cur + 1;
  }
#undef STAGE

  const int col_l = lane & 15;
  const int row_l = (lane >> 4) << 2;

  if constexpr (EPI == EPI_SCORES) {
    f16* Ch = (f16*)C + (size_t)bz * sC + (size_t)m0 * ldc + n0;
    float lmax = -3.402823466e38f, lmin = 3.402823466e38f;
#pragma unroll
    for (int m = 0; m < 4; ++m)
#pragma unroll
      for (int n = 0; n < 4; ++n)
#pragma unroll
        for (int r = 0; r < 4; ++r) {
          float val = acc[m][n][r] * scale;
          lmax = fmaxf(lmax, val); lmin = fminf(lmin, val);
          Ch[(size_t)(wm * 64 + m * 16 + row_l + r) * ldc + (wn * 64 + n * 16 + col_l)] = (f16)val;
        }
#pragma unroll
    for (int off = 32; off >= 1; off >>= 1) {
      lmax = fmaxf(lmax, __shfl_xor(lmax, off));
      lmin = fminf(lmin, __shfl_xor(lmin, off));
    }
    if (lane == 0) { redm[w] = lmax; redn[w] = lmin; }
    __syncthreads();
    if (tid == 0) {
      mmarr[lin]       = fmaxf(fmaxf(redm[0], redm[1]), fmaxf(redm[2], redm[3]));
      mmarr[nmm + lin] = fminf(fminf(redn[0], redn[1]), fminf(redn[2], redn[3]));
    }
  } else {
    f16* Ch = (f16*)C + (size_t)bz * sC + (size_t)m0 * ldc + n0;
#pragma unroll
    for (int m = 0; m < 4; ++m)
#pragma unroll
      for (int n = 0; n < 4; ++n)
#pragma unroll
        for (int r = 0; r < 4; ++r) {
          const int rr = wm * 64 + m * 16 + row_l + r;
          const int cc = wn * 64 + n * 16 + col_l;
          float val = acc[m][n][r];
          if constexpr (EPI == EPI_RELU) { val += bias[n0 + cc]; val = fmaxf(val, 0.0f); }
          if constexpr (EPI == EPI_BIASR) val += bias[m0 + rr];
          if constexpr (EPI == EPI_OUT)
            val += wfb[bz * 1024 + m0 + rr] * dvv[bz * 512 + n0 + cc];
          Ch[(size_t)rr * ldc + cc] = (f16)val;
        }
  }
}

// reduce per-block max/min -> fb scalar
__global__ __launch_bounds__(256)
void reduce_mm(const float* __restrict__ mmarr, int n,
               const float* __restrict__ fallback, float* __restrict__ fbv)
{
  __shared__ float rm[4], rn[4];
  const int lane = threadIdx.x & 63, w = threadIdx.x >> 6;
  float mx = -3.402823466e38f, mn = 3.402823466e38f;
  for (int i = threadIdx.x; i < n; i += 256) {
    mx = fmaxf(mx, mmarr[i]);
    mn = fminf(mn, mmarr[n + i]);
  }
#pragma unroll
  for (int off = 32; off >= 1; off >>= 1) {
    mx = fmaxf(mx, __shfl_xor(mx, off));
    mn = fminf(mn, __shfl_xor(mn, off));
  }
  if (lane == 0) { rm[w] = mx; rn[w] = mn; }
  __syncthreads();
  if (threadIdx.x == 0) {
    float gmax = fmaxf(fmaxf(rm[0], rm[1]), fmaxf(rm[2], rm[3]));
    float gmin = fminf(fminf(rn[0], rn[1]), fminf(rn[2], rn[3]));
    fbv[0] = 0.99f * fallback[0] + 0.005f * (gmax + gmin);
  }
}

// fused f32->f16 convert of q,k,v
__global__ __launch_bounds__(256)
void conv3_k(const float* __restrict__ a, const float* __restrict__ b,
             const float* __restrict__ c,
             f16* __restrict__ oa, f16* __restrict__ ob, f16* __restrict__ oc,
             int n4each)
{
  int i = blockIdx.x * 256 + threadIdx.x;
  int seg = i / n4each;
  int j = i - seg * n4each;
  const float* src = (seg == 0) ? a : ((seg == 1) ? b : c);
  f16* dst = (seg == 0) ? oa : ((seg == 1) ? ob : oc);
  float4 v = *(const float4*)(src + (size_t)j * 4);
  f16x4 o = { (f16)v.x, (f16)v.y, (f16)v.z, (f16)v.w };
  *(f16x4*)(dst + (size_t)j * 4) = o;
}

__global__ __launch_bounds__(256)
void convw_k(const float* __restrict__ wv, const float* __restrict__ w1,
             const float* __restrict__ w2,
             f16* __restrict__ owv, f16* __restrict__ ow1, f16* __restrict__ ow2)
{
  int i = blockIdx.x * 256 + threadIdx.x;   // 0..163839
  const float* src; f16* dst; int j;
  if (i < 65536)       { src = wv; dst = owv; j = i; }
  else if (i < 131072) { src = w1; dst = ow1; j = i - 65536; }
  else                 { src = w2; dst = ow2; j = i - 131072; }
  float4 v = *(const float4*)(src + (size_t)j * 4);
  f16x4 o = { (f16)v.x, (f16)v.y, (f16)v.z, (f16)v.w };
  *(f16x4*)(dst + (size_t)j * 4) = o;
}

// one block: count nonzero bytes of mask (dtype sniffing)
__global__ void init_count(const unsigned char* __restrict__ mask, unsigned* __restrict__ mm)
{
  __shared__ int red[256];
  int c = 0;
  for (int i = threadIdx.x; i < 16384; i += 256) c += (mask[i] != 0) ? 1 : 0;
  red[threadIdx.x] = c;
  __syncthreads();
  for (int s = 128; s > 0; s >>= 1) {
    if (threadIdx.x < s) red[threadIdx.x] += red[threadIdx.x + s];
    __syncthreads();
  }
  if (threadIdx.x == 0) mm[0] = (unsigned)red[0];
}

__global__ __launch_bounds__(256)
void softmax_rows(const f16* __restrict__ scores, const void* __restrict__ maskp,
                  const float* __restrict__ fbv, const unsigned* __restrict__ mm,
                  f16* __restrict__ Wt, float* __restrict__ wfb)
{
  __shared__ float red[8];
  const int row  = blockIdx.x;
  const int b    = row >> 10;
  const int tid  = threadIdx.x;
  const int lane = tid & 63, w = tid >> 6;
  const float fb = fbv[0];
  const unsigned mode = (mm[0] > 5000u) ? 1u : 0u;
  const f16* s = scores + (size_t)row * 1024;
  const int k0 = tid * 4;
  f16x4 sv = *(const f16x4*)(s + k0);
  float x[4];
  if (mode) {
    const unsigned char* m8 = (const unsigned char*)maskp + b * 1024 + k0;
    x[0] = m8[0] ? -1e9f : (float)sv[0];  x[1] = m8[1] ? -1e9f : (float)sv[1];
    x[2] = m8[2] ? -1e9f : (float)sv[2];  x[3] = m8[3] ? -1e9f : (float)sv[3];
  } else {
    const int* mi = (const int*)maskp + b * 1024 + k0;
    x[0] = mi[0] ? -1e9f : (float)sv[0];  x[1] = mi[1] ? -1e9f : (float)sv[1];
    x[2] = mi[2] ? -1e9f : (float)sv[2];  x[3] = mi[3] ? -1e9f : (float)sv[3];
  }
  float mx = fmaxf(fmaxf(x[0], x[1]), fmaxf(x[2], x[3]));
#pragma unroll
  for (int off = 32; off >= 1; off >>= 1) mx = fmaxf(mx, __shfl_xor(mx, off));
  if (lane == 0) red[w] = mx;
  __syncthreads();
  mx = fmaxf(fmaxf(fmaxf(red[0], red[1]), fmaxf(red[2], red[3])), fb);
  float e0 = expf(x[0] - mx), e1 = expf(x[1] - mx), e2 = expf(x[2] - mx), e3 = expf(x[3] - mx);
  float sum = (e0 + e1) + (e2 + e3);
#pragma unroll
  for (int off = 32; off >= 1; off >>= 1) sum += __shfl_xor(sum, off);
  if (lane == 0) red[4 + w] = sum;
  __syncthreads();
  float efb = expf(fb - mx);
  float Z = ((red[4] + red[5]) + (red[6] + red[7])) + efb;
  float inv = 1.0f / Z;
  f16x4 o = { (f16)(e0 * inv), (f16)(e1 * inv), (f16)(e2 * inv), (f16)(e3 * inv) };
  *(f16x4*)&Wt[(size_t)row * 1024 + k0] = o;
  if (tid == 0) wfb[row] = efb * inv;
}

// wave-per-output FC: Y[b,j] = act(X[b,:] . W[j,:] + bias[j])
// IN = 512 (8 floats/lane) or 256 (4 floats/lane). ACT: 0=none, 1=relu, 2=tanh.
template<int IN, int ACT>
__global__ __launch_bounds__(256)
void fc_wave(const float* __restrict__ X, const float* __restrict__ W,
             const float* __restrict__ bias, float* __restrict__ Y, int OutN)
{
  const int gw   = (blockIdx.x * 256 + threadIdx.x) >> 6;
  const int lane = threadIdx.x & 63;
  const int b = gw / OutN, j = gw - b * OutN;
  const float* x  = X + (size_t)b * IN;
  const float* wr = W + (size_t)j * IN;
  float s = 0.f;
  if constexpr (IN == 512) {
    const int o = lane * 8;
    float4 x0 = *(const float4*)(x + o),  x1 = *(const float4*)(x + o + 4);
    float4 w0 = *(const float4*)(wr + o), w1 = *(const float4*)(wr + o + 4);
    s = x0.x*w0.x + x0.y*w0.y + x0.z*w0.z + x0.w*w0.w
      + x1.x*w1.x + x1.y*w1.y + x1.z*w1.z + x1.w*w1.w;
  } else {
    const int o = lane * 4;
    float4 x0 = *(const float4*)(x + o);
    float4 w0 = *(const float4*)(wr + o);
    s = x0.x*w0.x + x0.y*w0.y + x0.z*w0.z + x0.w*w0.w;
  }
#pragma unroll
  for (int off = 32; off >= 1; off >>= 1) s += __shfl_xor(s, off);
  if (lane == 0) {
    float val = s + bias[ACT == 2 ? 0 : j];
    if constexpr (ACT == 1) val = fmaxf(val, 0.f);
    if constexpr (ACT == 2) val = tanhf(val);
    Y[gw] = val;
  }
}

__global__ __launch_bounds__(256)
void y_kernel(const f16* __restrict__ h2, const float* __restrict__ W3,
              const float* __restrict__ b3, float* __restrict__ outp)
{
  int row = blockIdx.x * 16 + (threadIdx.x >> 4);
  int l   = threadIdx.x & 15;
  const f16* h = h2 + (size_t)row * 256 + l * 16;
  float s = 0.f;
#pragma unroll
  for (int j = 0; j < 16; ++j) s += (float)h[j] * W3[l * 16 + j];
#pragma unroll
  for (int off = 1; off < 16; off <<= 1) s += __shfl_xor(s, off);
  if (l == 0) outp[row] = tanhf(s + b3[0]);
}

extern "C" void kernel_launch(void* const* d_in, const int* in_sizes, int n_in,
                              void* d_out, int out_size, void* d_ws, size_t ws_size,
                              hipStream_t stream) {
  const float* uq       = (const float*)d_in[0];
  const float* q        = (const float*)d_in[1];
  const float* kk       = (const float*)d_in[2];
  const float* v        = (const float*)d_in[3];
  const void*  mask     = d_in[4];
  const float* fallback = (const float*)d_in[5];
  const float* Wv = (const float*)d_in[6];
  const float* bv = (const float*)d_in[7];
  const float* Wf = (const float*)d_in[8];
  const float* bf = (const float*)d_in[9];
  const float* W1 = (const float*)d_in[10];
  const float* b1 = (const float*)d_in[11];
  const float* W2 = (const float*)d_in[12];
  const float* b2 = (const float*)d_in[13];
  const float* W3 = (const float*)d_in[14];
  const float* b3 = (const float*)d_in[15];
  float* outp = (float*)d_out;

  char* ws = (char*)d_ws;
  const size_t MB = 1ull << 20;
  // [0,32M): scores f16 (dead after softmax) -> h1b [0,16M), h2b [16,24M)
  f16*  scores = (f16*)ws;
  f16*  h1b  = (f16*)ws;
  f16*  h2b  = (f16*)(ws + 16 * MB);
  // [32,48M): vpt; [48,64M): outb
  f16*  vpt  = (f16*)(ws + 32 * MB);
  f16*  outb = (f16*)(ws + 48 * MB);
  // [64,112M): q16,k16,v16; wts reuses [64,96M) after scores GEMM
  f16*  q16  = (f16*)(ws + 64 * MB);
  f16*  wts  = (f16*)(ws + 64 * MB);
  f16*  k16  = (f16*)(ws + 80 * MB);
  f16*  v16  = (f16*)(ws + 96 * MB);
  char* cst  = ws + 112 * MB;
  f16*  Wv16 = (f16*)(cst);
  f16*  W116 = (f16*)(cst + 512 * 1024);
  f16*  W216 = (f16*)(cst + 1024 * 1024);
  float* dv   = (float*)(cst + 1280 * 1024);
  float* wfb  = (float*)(cst + 1312 * 1024);
  float* h1d  = (float*)(cst + 1376 * 1024);
  float* h2d  = (float*)(cst + 1408 * 1024);
  unsigned* mm = (unsigned*)(cst + 1424 * 1024);
  float* fbv   = (float*)(cst + 1428 * 1024);
  float* mmarr = (float*)(cst + 1432 * 1024);   // 2 * 1024 floats

  init_count<<<1, 256, 0, stream>>>((const unsigned char*)mask, mm);

  conv3_k<<<24576, 256, 0, stream>>>(q, kk, v, q16, k16, v16, 2097152);
  convw_k<<<640, 256, 0, stream>>>(Wv, W1, W2, Wv16, W116, W216);

  // dv = uq @ Wf^T + bf  (wave per output, 8192 waves)
  fc_wave<512, 0><<<2048, 256, 0, stream>>>(uq, Wf, bf, dv, 512);

  // scores = q @ k^T / sqrt(512) -> f16, per-block max/min
  gemm_bt<EPI_SCORES, true><<<1024, 256, 0, stream>>>(
      q16, k16, scores, 512, 512, 1024, 512,
      524288LL, 524288LL, 1048576LL,
      nullptr, 0.04419417382415922f, mmarr, 1024, nullptr, nullptr, 8, 64);

  reduce_mm<<<1, 256, 0, stream>>>(mmarr, 1024, fallback, fbv);

  softmax_rows<<<16384, 256, 0, stream>>>(scores, mask, fbv, mm, wts, wfb);

  // vpt[d][k] = sum_e Wv[d][e] v[k][e] + bv[d]
  gemm_bt<EPI_BIASR, true><<<512, 256, 0, stream>>>(
      Wv16, v16, vpt, 512, 512, 1024, 512,
      0LL, 524288LL, 524288LL,
      bv, 1.f, nullptr, 0, nullptr, nullptr, 8, 32);

  // out = weights @ vp + wfb*dv
  gemm_bt<EPI_OUT, true><<<512, 256, 0, stream>>>(
      wts, vpt, outb, 1024, 1024, 512, 1024,
      1048576LL, 524288LL, 524288LL,
      nullptr, 1.f, nullptr, 0, wfb, dv, 4, 32);

  // h1 = relu(out @ W1^T + b1)
  gemm_bt<EPI_RELU, false><<<512, 256, 0, stream>>>(
      outb, W116, h1b, 512, 512, 512, 512, 0LL, 0LL, 0LL,
      b1, 1.f, nullptr, 0, nullptr, nullptr, 4, 512);

  // h2 = relu(h1 @ W2^T + b2)
  gemm_bt<EPI_RELU, false><<<256, 256, 0, stream>>>(
      h1b, W216, h2b, 512, 512, 256, 512, 0LL, 0LL, 0LL,
      b2, 1.f, nullptr, 0, nullptr, nullptr, 2, 256);

  y_kernel<<<1024, 256, 0, stream>>>(h2b, W3, b3, outp);

  // default-values scorer branch (f32, wave-per-output)
  fc_wave<512, 1><<<2048, 256, 0, stream>>>(dv, W1, b1, h1d, 512);
  fc_wave<512, 1><<<1024, 256, 0, stream>>>(h1d, W2, b2, h2d, 256);
  fc_wave<256, 2><<<4, 256, 0, stream>>>(h2d, W3, b3, outp + 16384, 1);

  (void)in_sizes; (void)n_in; (void)out_size; (void)ws_size;
}

// Round 5
// 181.470 us; speedup vs baseline: 2.4768x; 1.0520x over previous
//
#include <hip/hip_runtime.h>

typedef _Float16 f16;
typedef f16  f16x8 __attribute__((ext_vector_type(8)));
typedef f16  f16x4 __attribute__((ext_vector_type(4)));
typedef float f32x4 __attribute__((ext_vector_type(4)));

__device__ __forceinline__ void gld_lds16(const f16* g, void* l) {
  __builtin_amdgcn_global_load_lds((const __attribute__((address_space(1))) void*)g,
                                   (__attribute__((address_space(3))) void*)l,
                                   16, 0, 0);
}

enum { EPI_SCORES = 0, EPI_RELU = 2, EPI_OUT = 3, EPI_BIASR = 4 };

// C[M,N] = A[M,K] @ B[N,K]^T, 128x128 tile, BK=32, 4 waves (2x2), 16x16x32 f16 MFMA.
// 3-stage LDS pipeline, counted vmcnt (never 0 mid-loop), raw s_barrier, swizzled LDS.
template<int EPI, bool XMAP>
__global__ __launch_bounds__(256)
void gemm_bt(const f16* __restrict__ A, const f16* __restrict__ B, void* __restrict__ C,
             int lda, int ldb, int ldc, int K,
             long long sA, long long sB, long long sC,
             const float* __restrict__ bias, float scale,
             float* __restrict__ mmarr, int nmm,
             const float* __restrict__ wfb, const float* __restrict__ dvv,
             int nx, int nbz)
{
  __shared__ __align__(16) f16 As[3][128][32];
  __shared__ __align__(16) f16 Bs[3][128][32];
  const int tid  = threadIdx.x;
  const int lane = tid & 63;
  const int w    = tid >> 6;
  const int wm   = w >> 1, wn = w & 1;

  const int lin = blockIdx.x;
  int bz, bj;
  if constexpr (XMAP) {
    const int xcd = lin & 7, rest = lin >> 3;
    const int grp = rest / nbz;
    bj = rest - grp * nbz;
    bz = xcd + (grp << 3);
  } else {
    bz = lin / nbz; bj = lin - bz * nbz;
  }
  const int m0 = (bj / nx) * 128, n0 = (bj % nx) * 128;
  const f16* Ab = A + (size_t)bz * sA + (size_t)m0 * lda;
  const f16* Bb = B + (size_t)bz * sB + (size_t)n0 * ldb;

  f32x4 acc[4][4] = {};
  const int nsteps = K >> 5;

#define STAGE(bufb, ks)                                                              \
  {                                                                                  \
    const int k0_ = (ks) << 5;                                                       \
    _Pragma("unroll")                                                                \
    for (int i = 0; i < 2; ++i) {                                                    \
      const int ci = i * 256 + tid;                                                  \
      const int r  = ci >> 2;                                                        \
      const int sg = (ci & 3) ^ ((r >> 1) & 3);                                      \
      gld_lds16(Ab + (size_t)r * lda + k0_ + sg * 8,                                 \
                (char*)As + (bufb) + (size_t)(i * 256 + w * 64) * 16);               \
      gld_lds16(Bb + (size_t)r * ldb + k0_ + sg * 8,                                 \
                (char*)Bs + (bufb) + (size_t)(i * 256 + w * 64) * 16);               \
    }                                                                                \
  }

  STAGE(0, 0)
  STAGE(8192, 1)

  const int elemoff = (((lane >> 4) ^ ((lane >> 1) & 3)) << 3);

  int cur = 0;
  for (int t = 0; t < nsteps; ++t) {
    if (t + 1 < nsteps) asm volatile("s_waitcnt vmcnt(4)" ::: "memory");
    else                asm volatile("s_waitcnt vmcnt(0)" ::: "memory");
    __builtin_amdgcn_s_barrier();
    __builtin_amdgcn_sched_barrier(0);
    int st = cur + 2; if (st >= 3) st -= 3;
    if (t + 2 < nsteps) STAGE(st * 8192, t + 2)
    f16x8 af[4], bfr[4];
#pragma unroll
    for (int m = 0; m < 4; ++m)
      af[m] = *(const f16x8*)&As[cur][wm * 64 + m * 16 + (lane & 15)][elemoff];
#pragma unroll
    for (int n = 0; n < 4; ++n)
      bfr[n] = *(const f16x8*)&Bs[cur][wn * 64 + n * 16 + (lane & 15)][elemoff];
    __builtin_amdgcn_s_setprio(1);
#pragma unroll
    for (int m = 0; m < 4; ++m)
#pragma unroll
      for (int n = 0; n < 4; ++n)
        acc[m][n] = __builtin_amdgcn_mfma_f32_16x16x32_f16(af[m], bfr[n], acc[m][n], 0, 0, 0);
    __builtin_amdgcn_s_setprio(0);
    cur = (cur + 1 == 3) ? 0 : cur + 1;
  }
#undef STAGE

  const int col_l = lane & 15;
  const int row_l = (lane >> 4) << 2;

  {
    f16* Ch = (f16*)C + (size_t)bz * sC + (size_t)m0 * ldc + n0;
#pragma unroll
    for (int m = 0; m < 4; ++m)
#pragma unroll
      for (int n = 0; n < 4; ++n)
#pragma unroll
        for (int r = 0; r < 4; ++r) {
          const int rr = wm * 64 + m * 16 + row_l + r;
          const int cc = wn * 64 + n * 16 + col_l;
          float val = acc[m][n][r];
          if constexpr (EPI == EPI_RELU) { val += bias[n0 + cc]; val = fmaxf(val, 0.0f); }
          if constexpr (EPI == EPI_BIASR) val += bias[m0 + rr];
          if constexpr (EPI == EPI_OUT)
            val += wfb[bz * 1024 + m0 + rr] * dvv[bz * 512 + n0 + cc];
          Ch[(size_t)rr * ldc + cc] = (f16)val;
        }
  }
  (void)scale; (void)mmarr; (void)nmm;
}

// 256x256 tile scores GEMM: C = (A @ B^T) * scale -> f16, per-block max/min.
// 8 waves (2m x 4n), BK=32, same 3-buffer / stage(t+2) / vmcnt(4) skeleton as gemm_bt.
// Fixed shape: lda=ldb=512 (K=512), ldc=1024, sA=sB=512K, sC=1M, grid 256 (4x4x16, XCD-mapped).
__global__ __launch_bounds__(512, 2)
void gemm256_scores(const f16* __restrict__ A, const f16* __restrict__ B, f16* __restrict__ C,
                    float scale, float* __restrict__ mmarr)
{
  __shared__ __align__(16) f16 As[3][256][32];
  __shared__ __align__(16) f16 Bs[3][256][32];
  __shared__ float redm[8], redn[8];
  const int tid  = threadIdx.x;
  const int lane = tid & 63;
  const int w    = tid >> 6;           // 0..7
  const int wm   = w >> 2, wn = w & 3; // 2 x 4
  const int lin  = blockIdx.x;
  const int xcd = lin & 7, rest = lin >> 3;
  const int bj  = rest & 15;
  const int bz  = xcd + ((rest >> 4) << 3);
  const int m0 = (bj >> 2) * 256, n0 = (bj & 3) * 256;
  const f16* Ab = A + (size_t)bz * 524288 + (size_t)m0 * 512;
  const f16* Bb = B + (size_t)bz * 524288 + (size_t)n0 * 512;

  f32x4 acc[8][4] = {};

#define STAGE2(bufb, ks)                                                             \
  {                                                                                  \
    const int k0_ = (ks) << 5;                                                       \
    _Pragma("unroll")                                                                \
    for (int i = 0; i < 2; ++i) {                                                    \
      const int ci = i * 512 + tid;                                                  \
      const int r  = ci >> 2;                                                        \
      const int sg = (ci & 3) ^ ((r >> 1) & 3);                                      \
      gld_lds16(Ab + (size_t)r * 512 + k0_ + sg * 8,                                 \
                (char*)As + (bufb) + (size_t)(i * 512 + w * 64) * 16);               \
      gld_lds16(Bb + (size_t)r * 512 + k0_ + sg * 8,                                 \
                (char*)Bs + (bufb) + (size_t)(i * 512 + w * 64) * 16);               \
    }                                                                                \
  }

  STAGE2(0, 0)
  STAGE2(16384, 1)

  const int elemoff = (((lane >> 4) ^ ((lane >> 1) & 3)) << 3);

  int cur = 0;
  for (int t = 0; t < 16; ++t) {
    if (t + 1 < 16) asm volatile("s_waitcnt vmcnt(4)" ::: "memory");
    else            asm volatile("s_waitcnt vmcnt(0)" ::: "memory");
    __builtin_amdgcn_s_barrier();
    __builtin_amdgcn_sched_barrier(0);
    int st = cur + 2; if (st >= 3) st -= 3;
    if (t + 2 < 16) STAGE2(st * 16384, t + 2)
    f16x8 af[8], bfr[4];
#pragma unroll
    for (int m = 0; m < 8; ++m)
      af[m] = *(const f16x8*)&As[cur][wm * 128 + m * 16 + (lane & 15)][elemoff];
#pragma unroll
    for (int n = 0; n < 4; ++n)
      bfr[n] = *(const f16x8*)&Bs[cur][wn * 64 + n * 16 + (lane & 15)][elemoff];
    __builtin_amdgcn_s_setprio(1);
#pragma unroll
    for (int m = 0; m < 8; ++m)
#pragma unroll
      for (int n = 0; n < 4; ++n)
        acc[m][n] = __builtin_amdgcn_mfma_f32_16x16x32_f16(af[m], bfr[n], acc[m][n], 0, 0, 0);
    __builtin_amdgcn_s_setprio(0);
    cur = (cur + 1 == 3) ? 0 : cur + 1;
  }
#undef STAGE2

  const int col_l = lane & 15;
  const int row_l = (lane >> 4) << 2;
  f16* Ch = C + (size_t)bz * 1048576 + (size_t)m0 * 1024 + n0;
  float lmax = -3.402823466e38f, lmin = 3.402823466e38f;
#pragma unroll
  for (int m = 0; m < 8; ++m)
#pragma unroll
    for (int n = 0; n < 4; ++n)
#pragma unroll
      for (int r = 0; r < 4; ++r) {
        float val = acc[m][n][r] * scale;
        lmax = fmaxf(lmax, val); lmin = fminf(lmin, val);
        Ch[(size_t)(wm * 128 + m * 16 + row_l + r) * 1024 + (wn * 64 + n * 16 + col_l)] = (f16)val;
      }
#pragma unroll
  for (int off = 32; off >= 1; off >>= 1) {
    lmax = fmaxf(lmax, __shfl_xor(lmax, off));
    lmin = fminf(lmin, __shfl_xor(lmin, off));
  }
  if (lane == 0) { redm[w] = lmax; redn[w] = lmin; }
  __syncthreads();
  if (tid == 0) {
    float gm = redm[0], gn = redn[0];
#pragma unroll
    for (int i = 1; i < 8; ++i) { gm = fmaxf(gm, redm[i]); gn = fminf(gn, redn[i]); }
    mmarr[lin] = gm; mmarr[256 + lin] = gn;
  }
}

// reduce per-block max/min -> fb scalar
__global__ __launch_bounds__(256)
void reduce_mm(const float* __restrict__ mmarr, int n,
               const float* __restrict__ fallback, float* __restrict__ fbv)
{
  __shared__ float rm[4], rn[4];
  const int lane = threadIdx.x & 63, w = threadIdx.x >> 6;
  float mx = -3.402823466e38f, mn = 3.402823466e38f;
  for (int i = threadIdx.x; i < n; i += 256) {
    mx = fmaxf(mx, mmarr[i]);
    mn = fminf(mn, mmarr[n + i]);
  }
#pragma unroll
  for (int off = 32; off >= 1; off >>= 1) {
    mx = fmaxf(mx, __shfl_xor(mx, off));
    mn = fminf(mn, __shfl_xor(mn, off));
  }
  if (lane == 0) { rm[w] = mx; rn[w] = mn; }
  __syncthreads();
  if (threadIdx.x == 0) {
    float gmax = fmaxf(fmaxf(rm[0], rm[1]), fmaxf(rm[2], rm[3]));
    float gmin = fminf(fminf(rn[0], rn[1]), fminf(rn[2], rn[3]));
    fbv[0] = 0.99f * fallback[0] + 0.005f * (gmax + gmin);
  }
}

// fused f32->f16 convert of q,k,v
__global__ __launch_bounds__(256)
void conv3_k(const float* __restrict__ a, const float* __restrict__ b,
             const float* __restrict__ c,
             f16* __restrict__ oa, f16* __restrict__ ob, f16* __restrict__ oc,
             int n4each)
{
  int i = blockIdx.x * 256 + threadIdx.x;
  int seg = i / n4each;
  int j = i - seg * n4each;
  const float* src = (seg == 0) ? a : ((seg == 1) ? b : c);
  f16* dst = (seg == 0) ? oa : ((seg == 1) ? ob : oc);
  float4 v = *(const float4*)(src + (size_t)j * 4);
  f16x4 o = { (f16)v.x, (f16)v.y, (f16)v.z, (f16)v.w };
  *(f16x4*)(dst + (size_t)j * 4) = o;
}

__global__ __launch_bounds__(256)
void convw_k(const float* __restrict__ wv, const float* __restrict__ w1,
             const float* __restrict__ w2,
             f16* __restrict__ owv, f16* __restrict__ ow1, f16* __restrict__ ow2)
{
  int i = blockIdx.x * 256 + threadIdx.x;   // 0..163839
  const float* src; f16* dst; int j;
  if (i < 65536)       { src = wv; dst = owv; j = i; }
  else if (i < 131072) { src = w1; dst = ow1; j = i - 65536; }
  else                 { src = w2; dst = ow2; j = i - 131072; }
  float4 v = *(const float4*)(src + (size_t)j * 4);
  f16x4 o = { (f16)v.x, (f16)v.y, (f16)v.z, (f16)v.w };
  *(f16x4*)(dst + (size_t)j * 4) = o;
}

// one block: count nonzero bytes of mask (dtype sniffing)
__global__ void init_count(const unsigned char* __restrict__ mask, unsigned* __restrict__ mm)
{
  __shared__ int red[256];
  int c = 0;
  for (int i = threadIdx.x; i < 16384; i += 256) c += (mask[i] != 0) ? 1 : 0;
  red[threadIdx.x] = c;
  __syncthreads();
  for (int s = 128; s > 0; s >>= 1) {
    if (threadIdx.x < s) red[threadIdx.x] += red[threadIdx.x + s];
    __syncthreads();
  }
  if (threadIdx.x == 0) mm[0] = (unsigned)red[0];
}

__global__ __launch_bounds__(256)
void softmax_rows(const f16* __restrict__ scores, const void* __restrict__ maskp,
                  const float* __restrict__ fbv, const unsigned* __restrict__ mm,
                  f16* __restrict__ Wt, float* __restrict__ wfb)
{
  __shared__ float red[8];
  const int row  = blockIdx.x;
  const int b    = row >> 10;
  const int tid  = threadIdx.x;
  const int lane = tid & 63, w = tid >> 6;
  const float fb = fbv[0];
  const unsigned mode = (mm[0] > 5000u) ? 1u : 0u;
  const f16* s = scores + (size_t)row * 1024;
  const int k0 = tid * 4;
  f16x4 sv = *(const f16x4*)(s + k0);
  float x[4];
  if (mode) {
    const unsigned char* m8 = (const unsigned char*)maskp + b * 1024 + k0;
    x[0] = m8[0] ? -1e9f : (float)sv[0];  x[1] = m8[1] ? -1e9f : (float)sv[1];
    x[2] = m8[2] ? -1e9f : (float)sv[2];  x[3] = m8[3] ? -1e9f : (float)sv[3];
  } else {
    const int* mi = (const int*)maskp + b * 1024 + k0;
    x[0] = mi[0] ? -1e9f : (float)sv[0];  x[1] = mi[1] ? -1e9f : (float)sv[1];
    x[2] = mi[2] ? -1e9f : (float)sv[2];  x[3] = mi[3] ? -1e9f : (float)sv[3];
  }
  float mx = fmaxf(fmaxf(x[0], x[1]), fmaxf(x[2], x[3]));
#pragma unroll
  for (int off = 32; off >= 1; off >>= 1) mx = fmaxf(mx, __shfl_xor(mx, off));
  if (lane == 0) red[w] = mx;
  __syncthreads();
  mx = fmaxf(fmaxf(fmaxf(red[0], red[1]), fmaxf(red[2], red[3])), fb);
  float e0 = expf(x[0] - mx), e1 = expf(x[1] - mx), e2 = expf(x[2] - mx), e3 = expf(x[3] - mx);
  float sum = (e0 + e1) + (e2 + e3);
#pragma unroll
  for (int off = 32; off >= 1; off >>= 1) sum += __shfl_xor(sum, off);
  if (lane == 0) red[4 + w] = sum;
  __syncthreads();
  float efb = expf(fb - mx);
  float Z = ((red[4] + red[5]) + (red[6] + red[7])) + efb;
  float inv = 1.0f / Z;
  f16x4 o = { (f16)(e0 * inv), (f16)(e1 * inv), (f16)(e2 * inv), (f16)(e3 * inv) };
  *(f16x4*)&Wt[(size_t)row * 1024 + k0] = o;
  if (tid == 0) wfb[row] = efb * inv;
}

// wave-per-output FC: Y[b,j] = act(X[b,:] . W[j,:] + bias[j])
template<int IN, int ACT>
__global__ __launch_bounds__(256)
void fc_wave(const float* __restrict__ X, const float* __restrict__ W,
             const float* __restrict__ bias, float* __restrict__ Y, int OutN)
{
  const int gw   = (blockIdx.x * 256 + threadIdx.x) >> 6;
  const int lane = threadIdx.x & 63;
  const int b = gw / OutN, j = gw - b * OutN;
  const float* x  = X + (size_t)b * IN;
  const float* wr = W + (size_t)j * IN;
  float s = 0.f;
  if constexpr (IN == 512) {
    const int o = lane * 8;
    float4 x0 = *(const float4*)(x + o),  x1 = *(const float4*)(x + o + 4);
    float4 w0 = *(const float4*)(wr + o), w1 = *(const float4*)(wr + o + 4);
    s = x0.x*w0.x + x0.y*w0.y + x0.z*w0.z + x0.w*w0.w
      + x1.x*w1.x + x1.y*w1.y + x1.z*w1.z + x1.w*w1.w;
  } else {
    const int o = lane * 4;
    float4 x0 = *(const float4*)(x + o);
    float4 w0 = *(const float4*)(wr + o);
    s = x0.x*w0.x + x0.y*w0.y + x0.z*w0.z + x0.w*w0.w;
  }
#pragma unroll
  for (int off = 32; off >= 1; off >>= 1) s += __shfl_xor(s, off);
  if (lane == 0) {
    float val = s + bias[ACT == 2 ? 0 : j];
    if constexpr (ACT == 1) val = fmaxf(val, 0.f);
    if constexpr (ACT == 2) val = tanhf(val);
    Y[gw] = val;
  }
}

__global__ __launch_bounds__(256)
void y_kernel(const f16* __restrict__ h2, const float* __restrict__ W3,
              const float* __restrict__ b3, float* __restrict__ outp)
{
  int row = blockIdx.x * 16 + (threadIdx.x >> 4);
  int l   = threadIdx.x & 15;
  const f16* h = h2 + (size_t)row * 256 + l * 16;
  float s = 0.f;
#pragma unroll
  for (int j = 0; j < 16; ++j) s += (float)h[j] * W3[l * 16 + j];
#pragma unroll
  for (int off = 1; off < 16; off <<= 1) s += __shfl_xor(s, off);
  if (l == 0) outp[row] = tanhf(s + b3[0]);
}

extern "C" void kernel_launch(void* const* d_in, const int* in_sizes, int n_in,
                              void* d_out, int out_size, void* d_ws, size_t ws_size,
                              hipStream_t stream) {
  const float* uq       = (const float*)d_in[0];
  const float* q        = (const float*)d_in[1];
  const float* kk       = (const float*)d_in[2];
  const float* v        = (const float*)d_in[3];
  const void*  mask     = d_in[4];
  const float* fallback = (const float*)d_in[5];
  const float* Wv = (const float*)d_in[6];
  const float* bv = (const float*)d_in[7];
  const float* Wf = (const float*)d_in[8];
  const float* bf = (const float*)d_in[9];
  const float* W1 = (const float*)d_in[10];
  const float* b1 = (const float*)d_in[11];
  const float* W2 = (const float*)d_in[12];
  const float* b2 = (const float*)d_in[13];
  const float* W3 = (const float*)d_in[14];
  const float* b3 = (const float*)d_in[15];
  float* outp = (float*)d_out;

  char* ws = (char*)d_ws;
  const size_t MB = 1ull << 20;
  f16*  scores = (f16*)ws;
  f16*  h1b  = (f16*)ws;
  f16*  h2b  = (f16*)(ws + 16 * MB);
  f16*  vpt  = (f16*)(ws + 32 * MB);
  f16*  outb = (f16*)(ws + 48 * MB);
  f16*  q16  = (f16*)(ws + 64 * MB);
  f16*  wts  = (f16*)(ws + 64 * MB);
  f16*  k16  = (f16*)(ws + 80 * MB);
  f16*  v16  = (f16*)(ws + 96 * MB);
  char* cst  = ws + 112 * MB;
  f16*  Wv16 = (f16*)(cst);
  f16*  W116 = (f16*)(cst + 512 * 1024);
  f16*  W216 = (f16*)(cst + 1024 * 1024);
  float* dv   = (float*)(cst + 1280 * 1024);
  float* wfb  = (float*)(cst + 1312 * 1024);
  float* h1d  = (float*)(cst + 1376 * 1024);
  float* h2d  = (float*)(cst + 1408 * 1024);
  unsigned* mm = (unsigned*)(cst + 1424 * 1024);
  float* fbv   = (float*)(cst + 1428 * 1024);
  float* mmarr = (float*)(cst + 1432 * 1024);   // 2 * 256 floats

  init_count<<<1, 256, 0, stream>>>((const unsigned char*)mask, mm);

  conv3_k<<<24576, 256, 0, stream>>>(q, kk, v, q16, k16, v16, 2097152);
  convw_k<<<640, 256, 0, stream>>>(Wv, W1, W2, Wv16, W116, W216);

  // dv = uq @ Wf^T + bf
  fc_wave<512, 0><<<2048, 256, 0, stream>>>(uq, Wf, bf, dv, 512);

  // scores = q @ k^T / sqrt(512) -> f16, per-block max/min (256x256 tiles, 8 waves)
  gemm256_scores<<<256, 512, 0, stream>>>(q16, k16, scores, 0.04419417382415922f, mmarr);

  reduce_mm<<<1, 256, 0, stream>>>(mmarr, 256, fallback, fbv);

  softmax_rows<<<16384, 256, 0, stream>>>(scores, mask, fbv, mm, wts, wfb);

  // vpt[d][k] = sum_e Wv[d][e] v[k][e] + bv[d]
  gemm_bt<EPI_BIASR, true><<<512, 256, 0, stream>>>(
      Wv16, v16, vpt, 512, 512, 1024, 512,
      0LL, 524288LL, 524288LL,
      bv, 1.f, nullptr, 0, nullptr, nullptr, 8, 32);

  // out = weights @ vp + wfb*dv
  gemm_bt<EPI_OUT, true><<<512, 256, 0, stream>>>(
      wts, vpt, outb, 1024, 1024, 512, 1024,
      1048576LL, 524288LL, 524288LL,
      nullptr, 1.f, nullptr, 0, wfb, dv, 4, 32);

  // h1 = relu(out @ W1^T + b1)
  gemm_bt<EPI_RELU, false><<<512, 256, 0, stream>>>(
      outb, W116, h1b, 512, 512, 512, 512, 0LL, 0LL, 0LL,
      b1, 1.f, nullptr, 0, nullptr, nullptr, 4, 512);

  // h2 = relu(h1 @ W2^T + b2)
  gemm_bt<EPI_RELU, false><<<256, 256, 0, stream>>>(
      h1b, W216, h2b, 512, 512, 256, 512, 0LL, 0LL, 0LL,
      b2, 1.f, nullptr, 0, nullptr, nullptr, 2, 256);

  y_kernel<<<1024, 256, 0, stream>>>(h2b, W3, b3, outp);

  // default-values scorer branch (f32, wave-per-output)
  fc_wave<512, 1><<<2048, 256, 0, stream>>>(dv, W1, b1, h1d, 512);
  fc_wave<512, 1><<<1024, 256, 0, stream>>>(h1d, W2, b2, h2d, 256);
  fc_wave<256, 2><<<4, 256, 0, stream>>>(h2d, W3, b3, outp + 16384, 1);

  (void)in_sizes; (void)n_in; (void)out_size; (void)ws_size;
}